// Round 5
// baseline (8376.011 us; speedup 1.0000x reference)
//
#include <hip/hip_runtime.h>
#include <hip/hip_bf16.h>

// Block_ViT on MI355X — round 5: fp32 inputs AND fp32 output (ref dtype), per-batch
// streaming (~25.5 MB ws). bf16 internal tensors (covered by bf16-ref tolerance).
// B=4, N=784 tokens, H=4 heads, Cs={64,128,256,512}, KV=960.

using bf16 = __hip_bfloat16;

__device__ inline float bf2f(unsigned short u) {
    return __uint_as_float(((unsigned int)u) << 16);
}
__device__ inline float ld1f(const float* p) { return *p; }
__device__ inline float ld1f(const bf16* p) { return bf2f(*(const unsigned short*)p); }
__device__ inline void st1(float* p, float v) { *p = v; }
__device__ inline void st1(bf16* p, float v) { *p = __float2bfloat16(v); }
__device__ inline float4 ld4f(const float* p) { return *(const float4*)p; }
__device__ inline float4 ld4f(const bf16* p) {
    ushort4 u = *(const ushort4*)p;
    return make_float4(bf2f(u.x), bf2f(u.y), bf2f(u.z), bf2f(u.w));
}

// ---- block reductions (256 threads = 4 waves) ----
__device__ inline float blockSum256(float v, float* red) {
    #pragma unroll
    for (int o = 32; o > 0; o >>= 1) v += __shfl_down(v, o);
    int t = threadIdx.x;
    if ((t & 63) == 0) red[t >> 6] = v;
    __syncthreads();
    float r = red[0] + red[1] + red[2] + red[3];
    __syncthreads();
    return r;
}
__device__ inline float blockMax256(float v, float* red) {
    #pragma unroll
    for (int o = 32; o > 0; o >>= 1) v = fmaxf(v, __shfl_down(v, o));
    int t = threadIdx.x;
    if ((t & 63) == 0) red[t >> 6] = v;
    __syncthreads();
    float r = fmaxf(fmaxf(red[0], red[1]), fmaxf(red[2], red[3]));
    __syncthreads();
    return r;
}

// ---- LayerNorm of concat over one batch: rows of [784, 960] -> bf16 ----
__global__ __launch_bounds__(256)
void ln_concat_kernel(const float* __restrict__ e1, const float* __restrict__ e2,
                      const float* __restrict__ e3, const float* __restrict__ e4,
                      const float* __restrict__ g, const float* __restrict__ b,
                      bf16* __restrict__ ea) {
    __shared__ float x[960];
    __shared__ float red[4];
    long row = blockIdx.x;
    int t = threadIdx.x;
    const float* p1 = e1 + row * 64;
    const float* p2 = e2 + row * 128;
    const float* p3 = e3 + row * 256;
    const float* p4 = e4 + row * 512;
    for (int i = t; i < 64;  i += 256) x[i]       = p1[i];
    for (int i = t; i < 128; i += 256) x[64 + i]  = p2[i];
    for (int i = t; i < 256; i += 256) x[192 + i] = p3[i];
    for (int i = t; i < 512; i += 256) x[448 + i] = p4[i];
    __syncthreads();
    float s = 0.f, q = 0.f;
    for (int i = t; i < 960; i += 256) { float v = x[i]; s += v; q += v * v; }
    float S1 = blockSum256(s, red), S2 = blockSum256(q, red);
    const float inv = 1.f / 960.f;
    float mu = S1 * inv;
    float r = rsqrtf(S2 * inv - mu * mu + 1e-6f);
    for (int i = t; i < 960; i += 256)
        ea[row * 960 + i] = __float2bfloat16((x[i] - mu) * r * g[i] + b[i]);
}

// ---- row LayerNorm: [784, C] fp32 -> fp32 ----
__global__ __launch_bounds__(256)
void ln_rows_kernel(const float* __restrict__ X, const float* __restrict__ g,
                    const float* __restrict__ b, float* __restrict__ Y, int C) {
    __shared__ float x[512];
    __shared__ float red[4];
    long row = blockIdx.x;
    int t = threadIdx.x;
    const float* xr = X + row * C;
    float s = 0.f, q = 0.f;
    for (int i = t; i < C; i += 256) { float v = xr[i]; x[i] = v; s += v; q += v * v; }
    float S1 = blockSum256(s, red), S2 = blockSum256(q, red);
    float mu = S1 / C;
    float r = rsqrtf(S2 / C - mu * mu + 1e-6f);
    for (int i = t; i < C; i += 256)
        Y[row * C + i] = (x[i] - mu) * r * g[i] + b[i];
}

// ---- NT GEMM: C[M,N] = A[M,K]@B[N,K]^T (+bias)(+gelu)(+res); M=784 guarded ----
// A fp32/bf16, B fp32 weights, bias/res fp32, out fp32/bf16. N%64==0, K%16==0.
template <class AT, class CT>
__global__ __launch_bounds__(256)
void gemm_nt_kernel(const AT* __restrict__ A, long sA,
                    const float* __restrict__ B, long sB,
                    CT* __restrict__ Cp, long sC,
                    const float* __restrict__ bias,
                    const float* __restrict__ res,
                    int M, int N, int K, int dogelu) {
    __shared__ float As[16][64];
    __shared__ float Bs[16][64];
    int tx = threadIdx.x, ty = threadIdx.y;
    int tid = ty * 16 + tx;
    long z = blockIdx.z;
    A += z * sA;
    B += z * sB;
    Cp += z * sC;
    int m0 = blockIdx.y * 64, n0 = blockIdx.x * 64;
    int lr = tid >> 2, lk = (tid & 3) * 4;
    int arow = m0 + lr;
    const AT* Ap = A + (long)arow * K + lk;
    const float* Bp = B + (long)(n0 + lr) * K + lk;
    float acc[4][4] = {};
    for (int k0 = 0; k0 < K; k0 += 16) {
        float4 av = (arow < M) ? ld4f(Ap + k0) : make_float4(0.f, 0.f, 0.f, 0.f);
        float4 bv = ld4f(Bp + k0);
        As[lk + 0][lr] = av.x; As[lk + 1][lr] = av.y;
        As[lk + 2][lr] = av.z; As[lk + 3][lr] = av.w;
        Bs[lk + 0][lr] = bv.x; Bs[lk + 1][lr] = bv.y;
        Bs[lk + 2][lr] = bv.z; Bs[lk + 3][lr] = bv.w;
        __syncthreads();
        #pragma unroll
        for (int kk = 0; kk < 16; kk++) {
            float4 a4 = *(const float4*)&As[kk][ty * 4];
            float4 b4 = *(const float4*)&Bs[kk][tx * 4];
            float aa[4] = {a4.x, a4.y, a4.z, a4.w};
            float bb[4] = {b4.x, b4.y, b4.z, b4.w};
            #pragma unroll
            for (int i = 0; i < 4; i++)
                #pragma unroll
                for (int j = 0; j < 4; j++) acc[i][j] += aa[i] * bb[j];
        }
        __syncthreads();
    }
    #pragma unroll
    for (int i = 0; i < 4; i++) {
        long m = m0 + ty * 4 + i;
        if (m < M) {
            #pragma unroll
            for (int j = 0; j < 4; j++) {
                long n = n0 + tx * 4 + j;
                float v = acc[i][j];
                if (bias) v += bias[n];
                if (dogelu) v = 0.5f * v * (1.f + erff(v * 0.70710678118f));
                if (res) v += res[m * N + n];
                st1(Cp + m * N + n, v);
            }
        }
    }
}

// ---- TN GEMM for scores (one batch): S[h][d,j] = scale*sum_n Q[h][n][d]*K[h][n][j] ----
// Q [4][784][C] bf16, K [4][784][960] bf16, S [4][C][960] bf16. Kdim=784 (%16==0).
__global__ __launch_bounds__(256)
void gemm_tn_kernel(const bf16* __restrict__ Q, const bf16* __restrict__ Kb,
                    bf16* __restrict__ S, int C, float scale) {
    __shared__ float As[16][64];
    __shared__ float Bs[16][64];
    int tx = threadIdx.x, ty = threadIdx.y;
    int tid = ty * 16 + tx;
    int h = blockIdx.z;
    const bf16* A = Q + (long)h * 784 * C;     // [784, C]
    const bf16* B = Kb + (long)h * 784 * 960;  // [784, 960]
    bf16* Sp = S + (long)h * C * 960;
    int d0 = blockIdx.y * 64, j0 = blockIdx.x * 64;
    int kr = tid >> 4, cq = (tid & 15) * 4;
    float acc[4][4] = {};
    for (int k0 = 0; k0 < 784; k0 += 16) {
        *(float4*)&As[kr][cq] = ld4f(A + (long)(k0 + kr) * C + d0 + cq);
        *(float4*)&Bs[kr][cq] = ld4f(B + (long)(k0 + kr) * 960 + j0 + cq);
        __syncthreads();
        #pragma unroll
        for (int kk = 0; kk < 16; kk++) {
            float4 a4 = *(const float4*)&As[kk][ty * 4];
            float4 b4 = *(const float4*)&Bs[kk][tx * 4];
            float aa[4] = {a4.x, a4.y, a4.z, a4.w};
            float bb[4] = {b4.x, b4.y, b4.z, b4.w};
            #pragma unroll
            for (int i = 0; i < 4; i++)
                #pragma unroll
                for (int j = 0; j < 4; j++) acc[i][j] += aa[i] * bb[j];
        }
        __syncthreads();
    }
    #pragma unroll
    for (int i = 0; i < 4; i++)
        #pragma unroll
        for (int j = 0; j < 4; j++)
            st1(Sp + (long)(d0 + ty * 4 + i) * 960 + j0 + tx * 4 + j, acc[i][j] * scale);
}

// ---- ctx GEMM (one batch): ctx[n][d] = 0.25 * sum_h sum_j V[h][n][j] * P[h][d][j] ----
// V [4][784][960] bf16, P [4][C][960] bf16, ctx [784,C] fp32. M=784 guarded.
__global__ __launch_bounds__(256)
void gemm_ctx_kernel(const bf16* __restrict__ V, const bf16* __restrict__ S,
                     float* __restrict__ ctx, int C) {
    __shared__ float As[16][64];
    __shared__ float Bs[16][64];
    int tx = threadIdx.x, ty = threadIdx.y;
    int tid = ty * 16 + tx;
    int n0 = blockIdx.y * 64, d0 = blockIdx.x * 64;
    int lr = tid >> 2, lk = (tid & 3) * 4;
    float acc[4][4] = {};
    for (int h = 0; h < 4; h++) {
        const bf16* Av = V + (long)h * 784 * 960;   // [784,960]
        const bf16* Bp = S + (long)h * C * 960;     // [C,960]
        for (int k0 = 0; k0 < 960; k0 += 16) {
            int row = n0 + lr;
            float4 av = (row < 784) ? ld4f(Av + (long)row * 960 + k0 + lk)
                                    : make_float4(0.f, 0.f, 0.f, 0.f);
            float4 bv = ld4f(Bp + (long)(d0 + lr) * 960 + k0 + lk);
            As[lk + 0][lr] = av.x; As[lk + 1][lr] = av.y;
            As[lk + 2][lr] = av.z; As[lk + 3][lr] = av.w;
            Bs[lk + 0][lr] = bv.x; Bs[lk + 1][lr] = bv.y;
            Bs[lk + 2][lr] = bv.z; Bs[lk + 3][lr] = bv.w;
            __syncthreads();
            #pragma unroll
            for (int kk = 0; kk < 16; kk++) {
                float4 a4 = *(const float4*)&As[kk][ty * 4];
                float4 b4 = *(const float4*)&Bs[kk][tx * 4];
                float aa[4] = {a4.x, a4.y, a4.z, a4.w};
                float bb[4] = {b4.x, b4.y, b4.z, b4.w};
                #pragma unroll
                for (int i = 0; i < 4; i++)
                    #pragma unroll
                    for (int j = 0; j < 4; j++) acc[i][j] += aa[i] * bb[j];
            }
            __syncthreads();
        }
    }
    #pragma unroll
    for (int i = 0; i < 4; i++) {
        int n = n0 + ty * 4 + i;
        if (n < 784) {
            #pragma unroll
            for (int j = 0; j < 4; j++)
                ctx[(long)n * C + d0 + tx * 4 + j] = acc[i][j] * 0.25f;
        }
    }
}

// ---- instance-norm reduce (one batch): one block per h, rstd over C*960 bf16 ----
__global__ __launch_bounds__(256)
void inorm_reduce_kernel(const bf16* __restrict__ S, float* __restrict__ rstd, int C) {
    __shared__ float red[4];
    int h = blockIdx.x;
    long n = (long)C * 960;
    const ushort4* p = (const ushort4*)((const unsigned short*)S + (long)h * n);
    long n4 = n >> 2;
    float s = 0.f, q = 0.f;
    for (long i = threadIdx.x; i < n4; i += 256) {
        ushort4 u = p[i];
        float a = bf2f(u.x), bb = bf2f(u.y), c = bf2f(u.z), d = bf2f(u.w);
        s += a + bb + c + d;
        q += a * a + bb * bb + c * c + d * d;
    }
    float S1 = blockSum256(s, red), S2 = blockSum256(q, red);
    if (threadIdx.x == 0) {
        float mu = S1 / n;
        rstd[h] = rsqrtf(S2 / n - mu * mu + 1e-5f);
    }
}

// ---- softmax over last dim (960); IN mean cancels per row (shift-invariance) ----
__global__ __launch_bounds__(256)
void softmax_kernel(bf16* __restrict__ S, const float* __restrict__ rstd, int C) {
    __shared__ float x[960];
    __shared__ float red[4];
    long r = blockIdx.x;          // [h][d] flattened, 4*C rows
    int t = threadIdx.x;
    float rs = rstd[r / C];
    bf16* row = S + r * 960;
    float mx = -3.4e38f;
    for (int i = t; i < 960; i += 256) {
        float v = ld1f(row + i) * rs; x[i] = v; mx = fmaxf(mx, v);
    }
    float M = blockMax256(mx, red);
    float s = 0.f;
    for (int i = t; i < 960; i += 256) { float e = __expf(x[i] - M); x[i] = e; s += e; }
    float Ssum = blockSum256(s, red);
    float inv = 1.f / Ssum;
    for (int i = t; i < 960; i += 256) row[i] = __float2bfloat16(x[i] * inv);
}

extern "C" void kernel_launch(void* const* d_in, const int* in_sizes, int n_in,
                              void* d_out, int out_size, void* d_ws, size_t ws_size,
                              hipStream_t stream) {
    (void)in_sizes; (void)n_in; (void)out_size; (void)ws_size;
    const int Cs[4] = {64, 128, 256, 512};
    const float *emb[4], *ang[4], *anb[4], *Wq[4], *Wo[4], *fng[4], *fnb[4], *w1[4], *b1[4], *w2[4], *b2[4];
    for (int i = 0; i < 4; i++) {
        const int base = i * 11;
        emb[i] = (const float*)d_in[base + 0];
        ang[i] = (const float*)d_in[base + 1];
        anb[i] = (const float*)d_in[base + 2];
        Wq[i]  = (const float*)d_in[base + 3];
        Wo[i]  = (const float*)d_in[base + 4];
        fng[i] = (const float*)d_in[base + 5];
        fnb[i] = (const float*)d_in[base + 6];
        w1[i]  = (const float*)d_in[base + 7];
        b1[i]  = (const float*)d_in[base + 8];
        w2[i]  = (const float*)d_in[base + 9];
        b2[i]  = (const float*)d_in[base + 10];
    }
    const float* anAg = (const float*)d_in[44];
    const float* anAb = (const float*)d_in[45];
    const float* Wk   = (const float*)d_in[46];
    const float* Wv   = (const float*)d_in[47];

    // per-batch ws layout (byte offsets, 16B-aligned), total ~25.5 MB
    char* wsb = (char*)d_ws;
    bf16*  ea   = (bf16*)(wsb + 0);            // [784,960]           1,505,280 B
    bf16*  Kb   = (bf16*)(wsb + 1505280);      // [4][784][960]       6,021,120 B
    bf16*  Vb   = (bf16*)(wsb + 7526400);      // [4][784][960]       6,021,120 B
    bf16*  Qb   = (bf16*)(wsb + 13547520);     // [4][784][C<=512] / hid [784][4C]  3,211,264 B
    bf16*  Sb   = (bf16*)(wsb + 16758784);     // [4][C<=512][960]    3,932,160 B
    float* cxb  = (float*)(wsb + 20690944);    // [784,C<=512]        1,605,632 B
    float* xb   = (float*)(wsb + 22296576);    // [784,C<=512]        1,605,632 B
    float* ctxb = (float*)(wsb + 23902208);    // [784,C<=512]        1,605,632 B
    float* rstd = (float*)(wsb + 25507840);    // [4]

    float* out = (float*)d_out;   // reference output dtype is float32
    const long ooff[4] = {0, 200704, 602112, 1404928};
    const float scale = 0.03227486121f;  // 1/sqrt(960)
    dim3 blk2(16, 16);

    for (int b = 0; b < 4; b++) {
        const float* eb[4];
        for (int i = 0; i < 4; i++) eb[i] = emb[i] + (long)b * 784 * Cs[i];

        ln_concat_kernel<<<784, 256, 0, stream>>>(eb[0], eb[1], eb[2], eb[3], anAg, anAb, ea);
        gemm_nt_kernel<bf16, bf16><<<dim3(15, 13, 4), blk2, 0, stream>>>(
            ea, 0, Wk, 921600, Kb, 784L * 960, nullptr, nullptr, 784, 960, 960, 0);
        gemm_nt_kernel<bf16, bf16><<<dim3(15, 13, 4), blk2, 0, stream>>>(
            ea, 0, Wv, 921600, Vb, 784L * 960, nullptr, nullptr, 784, 960, 960, 0);

        for (int i = 0; i < 4; i++) {
            const int C = Cs[i];
            // cx = LN(emb_i[b])  (fp32)
            ln_rows_kernel<<<784, 256, 0, stream>>>(eb[i], ang[i], anb[i], cxb, C);
            // Q[h] = cx @ Wq[h]^T  (bf16)
            gemm_nt_kernel<float, bf16><<<dim3(C / 64, 13, 4), blk2, 0, stream>>>(
                cxb, 0, Wq[i], (long)C * C, Qb, 784L * C, nullptr, nullptr, 784, C, C, 0);
            // scores = scale * Q^T K  (bf16)
            gemm_tn_kernel<<<dim3(15, C / 64, 4), blk2, 0, stream>>>(Qb, Kb, Sb, C, scale);
            // instance-norm rstd + softmax (in place)
            inorm_reduce_kernel<<<4, 256, 0, stream>>>(Sb, rstd, C);
            softmax_kernel<<<4 * C, 256, 0, stream>>>(Sb, rstd, C);
            // ctx = (1/H) sum_h P V  (fp32)
            gemm_ctx_kernel<<<dim3(C / 64, 13, 1), blk2, 0, stream>>>(Vb, Sb, ctxb, C);
            // x = emb + ctx @ Wo^T  (fp32)
            gemm_nt_kernel<float, float><<<dim3(C / 64, 13, 1), blk2, 0, stream>>>(
                ctxb, 0, Wo[i], 0, xb, 0, nullptr, eb[i], 784, C, C, 0);
            // lnx = LN(x)  (fp32)
            ln_rows_kernel<<<784, 256, 0, stream>>>(xb, fng[i], fnb[i], cxb, C);
            // hid = gelu(lnx @ w1^T + b1)  (bf16)
            gemm_nt_kernel<float, bf16><<<dim3(4 * C / 64, 13, 1), blk2, 0, stream>>>(
                cxb, 0, w1[i], 0, Qb, 0, b1[i], nullptr, 784, 4 * C, C, 1);
            // out = x + hid @ w2^T + b2  (fp32 store to d_out)
            gemm_nt_kernel<bf16, float><<<dim3(C / 64, 13, 1), blk2, 0, stream>>>(
                Qb, 0, w2[i], 0, out + ooff[i] + (long)b * 784 * C, 0, b2[i], xb,
                784, C, 4 * C, 0);
        }
    }
}

// Round 6
// 2420.244 us; speedup vs baseline: 3.4608x; 3.4608x over previous
//
#include <hip/hip_runtime.h>
#include <hip/hip_bf16.h>

// Block_ViT on MI355X — round 6: batch-fused grids (NB=4 if ws fits, else per-batch),
// two-stage ctx GEMM + two-stage instance-norm. fp32 in/out, bf16 internals.
// B=4, N=784 tokens/batch, H=4 heads, Cs={64,128,256,512}, KV=960.

using bf16 = __hip_bfloat16;

__device__ inline float bf2f(unsigned short u) {
    return __uint_as_float(((unsigned int)u) << 16);
}
__device__ inline float ld1f(const float* p) { return *p; }
__device__ inline float ld1f(const bf16* p) { return bf2f(*(const unsigned short*)p); }
__device__ inline void st1(float* p, float v) { *p = v; }
__device__ inline void st1(bf16* p, float v) { *p = __float2bfloat16(v); }
__device__ inline float4 ld4f(const float* p) { return *(const float4*)p; }
__device__ inline float4 ld4f(const bf16* p) {
    ushort4 u = *(const ushort4*)p;
    return make_float4(bf2f(u.x), bf2f(u.y), bf2f(u.z), bf2f(u.w));
}

// ---- block reductions (256 threads = 4 waves) ----
__device__ inline float blockSum256(float v, float* red) {
    #pragma unroll
    for (int o = 32; o > 0; o >>= 1) v += __shfl_down(v, o);
    int t = threadIdx.x;
    if ((t & 63) == 0) red[t >> 6] = v;
    __syncthreads();
    float r = red[0] + red[1] + red[2] + red[3];
    __syncthreads();
    return r;
}
__device__ inline float blockMax256(float v, float* red) {
    #pragma unroll
    for (int o = 32; o > 0; o >>= 1) v = fmaxf(v, __shfl_down(v, o));
    int t = threadIdx.x;
    if ((t & 63) == 0) red[t >> 6] = v;
    __syncthreads();
    float r = fmaxf(fmaxf(red[0], red[1]), fmaxf(red[2], red[3]));
    __syncthreads();
    return r;
}

// ---- LayerNorm of concat: rows of [NT, 960] -> bf16 (batches contiguous) ----
__global__ __launch_bounds__(256)
void ln_concat_kernel(const float* __restrict__ e1, const float* __restrict__ e2,
                      const float* __restrict__ e3, const float* __restrict__ e4,
                      const float* __restrict__ g, const float* __restrict__ b,
                      bf16* __restrict__ ea) {
    __shared__ float x[960];
    __shared__ float red[4];
    long row = blockIdx.x;
    int t = threadIdx.x;
    const float* p1 = e1 + row * 64;
    const float* p2 = e2 + row * 128;
    const float* p3 = e3 + row * 256;
    const float* p4 = e4 + row * 512;
    for (int i = t; i < 64;  i += 256) x[i]       = p1[i];
    for (int i = t; i < 128; i += 256) x[64 + i]  = p2[i];
    for (int i = t; i < 256; i += 256) x[192 + i] = p3[i];
    for (int i = t; i < 512; i += 256) x[448 + i] = p4[i];
    __syncthreads();
    float s = 0.f, q = 0.f;
    for (int i = t; i < 960; i += 256) { float v = x[i]; s += v; q += v * v; }
    float S1 = blockSum256(s, red), S2 = blockSum256(q, red);
    const float inv = 1.f / 960.f;
    float mu = S1 * inv;
    float r = rsqrtf(S2 * inv - mu * mu + 1e-6f);
    for (int i = t; i < 960; i += 256)
        ea[row * 960 + i] = __float2bfloat16((x[i] - mu) * r * g[i] + b[i]);
}

// ---- row LayerNorm: [NT, C] fp32 -> fp32 ----
__global__ __launch_bounds__(256)
void ln_rows_kernel(const float* __restrict__ X, const float* __restrict__ g,
                    const float* __restrict__ b, float* __restrict__ Y, int C) {
    __shared__ float x[512];
    __shared__ float red[4];
    long row = blockIdx.x;
    int t = threadIdx.x;
    const float* xr = X + row * C;
    float s = 0.f, q = 0.f;
    for (int i = t; i < C; i += 256) { float v = xr[i]; x[i] = v; s += v; q += v * v; }
    float S1 = blockSum256(s, red), S2 = blockSum256(q, red);
    float mu = S1 / C;
    float r = rsqrtf(S2 / C - mu * mu + 1e-6f);
    for (int i = t; i < C; i += 256)
        Y[row * C + i] = (x[i] - mu) * r * g[i] + b[i];
}

// ---- NT GEMM: C[M,N] = A[M,K]@B[N,K]^T (+bias)(+gelu)(+res); M guarded ----
template <class AT, class CT>
__global__ __launch_bounds__(256)
void gemm_nt_kernel(const AT* __restrict__ A, long sA,
                    const float* __restrict__ B, long sB,
                    CT* __restrict__ Cp, long sC,
                    const float* __restrict__ bias,
                    const float* __restrict__ res,
                    int M, int N, int K, int dogelu) {
    __shared__ float As[16][64];
    __shared__ float Bs[16][64];
    int tx = threadIdx.x, ty = threadIdx.y;
    int tid = ty * 16 + tx;
    long z = blockIdx.z;
    A += z * sA;
    B += z * sB;
    Cp += z * sC;
    int m0 = blockIdx.y * 64, n0 = blockIdx.x * 64;
    int lr = tid >> 2, lk = (tid & 3) * 4;
    int arow = m0 + lr;
    const AT* Ap = A + (long)arow * K + lk;
    const float* Bp = B + (long)(n0 + lr) * K + lk;
    float acc[4][4] = {};
    for (int k0 = 0; k0 < K; k0 += 16) {
        float4 av = (arow < M) ? ld4f(Ap + k0) : make_float4(0.f, 0.f, 0.f, 0.f);
        float4 bv = ld4f(Bp + k0);
        As[lk + 0][lr] = av.x; As[lk + 1][lr] = av.y;
        As[lk + 2][lr] = av.z; As[lk + 3][lr] = av.w;
        Bs[lk + 0][lr] = bv.x; Bs[lk + 1][lr] = bv.y;
        Bs[lk + 2][lr] = bv.z; Bs[lk + 3][lr] = bv.w;
        __syncthreads();
        #pragma unroll
        for (int kk = 0; kk < 16; kk++) {
            float4 a4 = *(const float4*)&As[kk][ty * 4];
            float4 b4 = *(const float4*)&Bs[kk][tx * 4];
            float aa[4] = {a4.x, a4.y, a4.z, a4.w};
            float bb[4] = {b4.x, b4.y, b4.z, b4.w};
            #pragma unroll
            for (int i = 0; i < 4; i++)
                #pragma unroll
                for (int j = 0; j < 4; j++) acc[i][j] += aa[i] * bb[j];
        }
        __syncthreads();
    }
    #pragma unroll
    for (int i = 0; i < 4; i++) {
        long m = m0 + ty * 4 + i;
        if (m < M) {
            #pragma unroll
            for (int j = 0; j < 4; j++) {
                long n = n0 + tx * 4 + j;
                float v = acc[i][j];
                if (bias) v += bias[n];
                if (dogelu) v = 0.5f * v * (1.f + erff(v * 0.70710678118f));
                if (res) v += res[m * N + n];
                st1(Cp + m * N + n, v);
            }
        }
    }
}

// ---- TN GEMM scores: z=b*4+h; S[z][d,j] = scale*sum_n Q[h][b*784+n][d]*K[h][b*784+n][j] ----
// Q [4][NT][C], K [4][NT][960], S [z][C][960] bf16. Kdim=784.
__global__ __launch_bounds__(256)
void gemm_tn_kernel(const bf16* __restrict__ Q, const bf16* __restrict__ Kb,
                    bf16* __restrict__ S, int C, int NT, float scale) {
    __shared__ float As[16][64];
    __shared__ float Bs[16][64];
    int tx = threadIdx.x, ty = threadIdx.y;
    int tid = ty * 16 + tx;
    int z = blockIdx.z, h = z & 3, b = z >> 2;
    const bf16* A = Q + ((long)h * NT + (long)b * 784) * C;
    const bf16* B = Kb + ((long)h * NT + (long)b * 784) * 960;
    bf16* Sp = S + (long)z * C * 960;
    int d0 = blockIdx.y * 64, j0 = blockIdx.x * 64;
    int kr = tid >> 4, cq = (tid & 15) * 4;
    float acc[4][4] = {};
    for (int k0 = 0; k0 < 784; k0 += 16) {
        *(float4*)&As[kr][cq] = ld4f(A + (long)(k0 + kr) * C + d0 + cq);
        *(float4*)&Bs[kr][cq] = ld4f(B + (long)(k0 + kr) * 960 + j0 + cq);
        __syncthreads();
        #pragma unroll
        for (int kk = 0; kk < 16; kk++) {
            float4 a4 = *(const float4*)&As[kk][ty * 4];
            float4 b4 = *(const float4*)&Bs[kk][tx * 4];
            float aa[4] = {a4.x, a4.y, a4.z, a4.w};
            float bb[4] = {b4.x, b4.y, b4.z, b4.w};
            #pragma unroll
            for (int i = 0; i < 4; i++)
                #pragma unroll
                for (int j = 0; j < 4; j++) acc[i][j] += aa[i] * bb[j];
        }
        __syncthreads();
    }
    #pragma unroll
    for (int i = 0; i < 4; i++)
        #pragma unroll
        for (int j = 0; j < 4; j++)
            st1(Sp + (long)(d0 + ty * 4 + i) * 960 + j0 + tx * 4 + j, acc[i][j] * scale);
}

// ---- per-head ctx GEMM: z=b*4+h; tmp[h][b*784+n][d] = sum_j V[h][b*784+n][j]*P[z][d][j] ----
__global__ __launch_bounds__(256)
void gemm_ctxh_kernel(const bf16* __restrict__ V, const bf16* __restrict__ S,
                      bf16* __restrict__ tmp, int C, int NT) {
    __shared__ float As[16][64];
    __shared__ float Bs[16][64];
    int tx = threadIdx.x, ty = threadIdx.y;
    int tid = ty * 16 + tx;
    int z = blockIdx.z, h = z & 3, b = z >> 2;
    const bf16* Av = V + ((long)h * NT + (long)b * 784) * 960;   // [784,960]
    const bf16* Bp = S + (long)z * C * 960;                      // [C,960]
    bf16* Op = tmp + ((long)h * NT + (long)b * 784) * C;         // [784,C]
    int n0 = blockIdx.y * 64, d0 = blockIdx.x * 64;
    int lr = tid >> 2, lk = (tid & 3) * 4;
    float acc[4][4] = {};
    for (int k0 = 0; k0 < 960; k0 += 16) {
        int row = n0 + lr;
        float4 av = (row < 784) ? ld4f(Av + (long)row * 960 + k0 + lk)
                                : make_float4(0.f, 0.f, 0.f, 0.f);
        float4 bv = ld4f(Bp + (long)(d0 + lr) * 960 + k0 + lk);
        As[lk + 0][lr] = av.x; As[lk + 1][lr] = av.y;
        As[lk + 2][lr] = av.z; As[lk + 3][lr] = av.w;
        Bs[lk + 0][lr] = bv.x; Bs[lk + 1][lr] = bv.y;
        Bs[lk + 2][lr] = bv.z; Bs[lk + 3][lr] = bv.w;
        __syncthreads();
        #pragma unroll
        for (int kk = 0; kk < 16; kk++) {
            float4 a4 = *(const float4*)&As[kk][ty * 4];
            float4 b4 = *(const float4*)&Bs[kk][tx * 4];
            float aa[4] = {a4.x, a4.y, a4.z, a4.w};
            float bb[4] = {b4.x, b4.y, b4.z, b4.w};
            #pragma unroll
            for (int i = 0; i < 4; i++)
                #pragma unroll
                for (int j = 0; j < 4; j++) acc[i][j] += aa[i] * bb[j];
        }
        __syncthreads();
    }
    #pragma unroll
    for (int i = 0; i < 4; i++) {
        int n = n0 + ty * 4 + i;
        if (n < 784) {
            #pragma unroll
            for (int j = 0; j < 4; j++)
                st1(Op + (long)n * C + d0 + tx * 4 + j, acc[i][j]);
        }
    }
}

// ---- ctx head-sum: ctx[i] = 0.25*sum_h tmp[h][i], vectorized x4 ----
__global__ __launch_bounds__(256)
void ctx_sum_kernel(const bf16* __restrict__ tmp, float* __restrict__ ctx, long NTC) {
    long i = ((long)blockIdx.x * 256 + threadIdx.x) * 4;
    float4 a = ld4f(tmp + i);
    float4 b = ld4f(tmp + NTC + i);
    float4 c = ld4f(tmp + 2 * NTC + i);
    float4 d = ld4f(tmp + 3 * NTC + i);
    float4 o;
    o.x = (a.x + b.x + c.x + d.x) * 0.25f;
    o.y = (a.y + b.y + c.y + d.y) * 0.25f;
    o.z = (a.z + b.z + c.z + d.z) * 0.25f;
    o.w = (a.w + b.w + c.w + d.w) * 0.25f;
    *(float4*)(ctx + i) = o;
}

// ---- instance-norm partial reduce: 12 parts per z; part sums of chunk ----
__global__ __launch_bounds__(256)
void inorm_part_kernel(const bf16* __restrict__ S, float2* __restrict__ part, int C) {
    __shared__ float red[4];
    int blk = blockIdx.x;
    int z = blk / 12, p = blk % 12;
    long n = (long)C * 960;
    long chunk = n / 12;
    const ushort4* base = (const ushort4*)((const unsigned short*)S + (long)z * n + p * chunk);
    long c4 = chunk >> 2;
    float s = 0.f, q = 0.f;
    for (long i = threadIdx.x; i < c4; i += 256) {
        ushort4 u = base[i];
        float a = bf2f(u.x), b = bf2f(u.y), c = bf2f(u.z), d = bf2f(u.w);
        s += a + b + c + d;
        q += a * a + b * b + c * c + d * d;
    }
    float S1 = blockSum256(s, red), S2 = blockSum256(q, red);
    if (threadIdx.x == 0) part[blk] = make_float2(S1, S2);
}
__global__ __launch_bounds__(64)
void inorm_fin_kernel(const float2* __restrict__ part, float* __restrict__ rstd,
                      int C, int nz) {
    int t = threadIdx.x;
    if (t < nz) {
        float s = 0.f, q = 0.f;
        for (int j = 0; j < 12; j++) { float2 v = part[t * 12 + j]; s += v.x; q += v.y; }
        float n = (float)C * 960.f;
        float mu = s / n;
        rstd[t] = rsqrtf(q / n - mu * mu + 1e-5f);
    }
}

// ---- softmax over last dim (960); IN mean cancels per row (shift-invariance) ----
__global__ __launch_bounds__(256)
void softmax_kernel(bf16* __restrict__ S, const float* __restrict__ rstd, int C) {
    __shared__ float x[960];
    __shared__ float red[4];
    long r = blockIdx.x;          // [z][d] flattened
    int t = threadIdx.x;
    float rs = rstd[r / C];
    bf16* row = S + r * 960;
    float mx = -3.4e38f;
    for (int i = t; i < 960; i += 256) {
        float v = ld1f(row + i) * rs; x[i] = v; mx = fmaxf(mx, v);
    }
    float M = blockMax256(mx, red);
    float s = 0.f;
    for (int i = t; i < 960; i += 256) { float e = __expf(x[i] - M); x[i] = e; s += e; }
    float Ssum = blockSum256(s, red);
    float inv = 1.f / Ssum;
    for (int i = t; i < 960; i += 256) row[i] = __float2bfloat16(x[i] * inv);
}

extern "C" void kernel_launch(void* const* d_in, const int* in_sizes, int n_in,
                              void* d_out, int out_size, void* d_ws, size_t ws_size,
                              hipStream_t stream) {
    (void)in_sizes; (void)n_in; (void)out_size;
    const int Cs[4] = {64, 128, 256, 512};
    const float *emb[4], *ang[4], *anb[4], *Wq[4], *Wo[4], *fng[4], *fnb[4], *w1[4], *b1[4], *w2[4], *b2[4];
    for (int i = 0; i < 4; i++) {
        const int base = i * 11;
        emb[i] = (const float*)d_in[base + 0];
        ang[i] = (const float*)d_in[base + 1];
        anb[i] = (const float*)d_in[base + 2];
        Wq[i]  = (const float*)d_in[base + 3];
        Wo[i]  = (const float*)d_in[base + 4];
        fng[i] = (const float*)d_in[base + 5];
        fnb[i] = (const float*)d_in[base + 6];
        w1[i]  = (const float*)d_in[base + 7];
        b1[i]  = (const float*)d_in[base + 8];
        w2[i]  = (const float*)d_in[base + 9];
        b2[i]  = (const float*)d_in[base + 10];
    }
    const float* anAg = (const float*)d_in[44];
    const float* anAb = (const float*)d_in[45];
    const float* Wk   = (const float*)d_in[46];
    const float* Wv   = (const float*)d_in[47];

    // Pick batch-chunk size: NB=4 (~102.1 MB) if ws allows, else NB=1 (~25.6 MB).
    const int NB = (ws_size >= (size_t)102200000) ? 4 : 1;
    const int NT = NB * 784;                 // token rows per chunk
    const int GY = (NT + 63) / 64;           // 49 or 13
    // ws layout (bytes)
    char* wsb = (char*)d_ws;
    bf16*   ea   = (bf16*)(wsb);
    bf16*   Kb   = (bf16*)(wsb + (size_t)1920 * NT);
    bf16*   Vb   = (bf16*)(wsb + (size_t)9600 * NT);
    bf16*   Qb   = (bf16*)(wsb + (size_t)17280 * NT);                 // Q / ctx-tmp / hid
    bf16*   Sb   = (bf16*)(wsb + (size_t)21376 * NT);
    char*   p0   = wsb + (size_t)21376 * NT + (size_t)NB * 3932160;
    float*  cxb  = (float*)(p0);
    float*  xb   = (float*)(p0 + (size_t)2048 * NT);
    float*  ctxb = (float*)(p0 + (size_t)4096 * NT);
    float2* part = (float2*)(p0 + (size_t)6144 * NT);
    float*  rstd = (float*)(p0 + (size_t)6144 * NT + 2048);

    float* out = (float*)d_out;
    const long ooff[4] = {0, 200704, 602112, 1404928};
    const float scale = 0.03227486121f;  // 1/sqrt(960)
    dim3 blk2(16, 16);

    for (int b0 = 0; b0 < 4; b0 += NB) {
        const float* eb[4];
        for (int i = 0; i < 4; i++) eb[i] = emb[i] + (long)b0 * 784 * Cs[i];

        ln_concat_kernel<<<NT, 256, 0, stream>>>(eb[0], eb[1], eb[2], eb[3], anAg, anAb, ea);
        gemm_nt_kernel<bf16, bf16><<<dim3(15, GY, 4), blk2, 0, stream>>>(
            ea, 0, Wk, 921600, Kb, (long)NT * 960, nullptr, nullptr, NT, 960, 960, 0);
        gemm_nt_kernel<bf16, bf16><<<dim3(15, GY, 4), blk2, 0, stream>>>(
            ea, 0, Wv, 921600, Vb, (long)NT * 960, nullptr, nullptr, NT, 960, 960, 0);

        for (int i = 0; i < 4; i++) {
            const int C = Cs[i];
            // cx = LN(emb_i)  (fp32)
            ln_rows_kernel<<<NT, 256, 0, stream>>>(eb[i], ang[i], anb[i], cxb, C);
            // Q[h] = cx @ Wq[h]^T  (bf16)
            gemm_nt_kernel<float, bf16><<<dim3(C / 64, GY, 4), blk2, 0, stream>>>(
                cxb, 0, Wq[i], (long)C * C, Qb, (long)NT * C, nullptr, nullptr, NT, C, C, 0);
            // scores = scale * Q^T K  (bf16)
            gemm_tn_kernel<<<dim3(15, C / 64, NB * 4), blk2, 0, stream>>>(
                Qb, Kb, Sb, C, NT, scale);
            // instance-norm rstd (two-stage) + softmax (in place)
            inorm_part_kernel<<<NB * 4 * 12, 256, 0, stream>>>(Sb, part, C);
            inorm_fin_kernel<<<1, 64, 0, stream>>>(part, rstd, C, NB * 4);
            softmax_kernel<<<NB * 4 * C, 256, 0, stream>>>(Sb, rstd, C);
            // per-head ctx into Qb (Q no longer needed), then head-sum -> ctxb fp32
            gemm_ctxh_kernel<<<dim3(C / 64, 13, NB * 4), blk2, 0, stream>>>(
                Vb, Sb, Qb, C, NT);
            ctx_sum_kernel<<<(int)(((long)NT * C) / 1024), 256, 0, stream>>>(
                Qb, ctxb, (long)NT * C);
            // x = emb + ctx @ Wo^T  (fp32)
            gemm_nt_kernel<float, float><<<dim3(C / 64, GY, 1), blk2, 0, stream>>>(
                ctxb, 0, Wo[i], 0, xb, 0, nullptr, eb[i], NT, C, C, 0);
            // lnx = LN(x)  (fp32)
            ln_rows_kernel<<<NT, 256, 0, stream>>>(xb, fng[i], fnb[i], cxb, C);
            // hid = gelu(lnx @ w1^T + b1)  (bf16, into Qb)
            gemm_nt_kernel<float, bf16><<<dim3(4 * C / 64, GY, 1), blk2, 0, stream>>>(
                cxb, 0, w1[i], 0, Qb, 0, b1[i], nullptr, NT, 4 * C, C, 1);
            // out = x + hid @ w2^T + b2  (fp32 store to d_out)
            gemm_nt_kernel<bf16, float><<<dim3(C / 64, GY, 1), blk2, 0, stream>>>(
                Qb, 0, w2[i], 0, out + ooff[i] + (long)b0 * 784 * C, 0, b2[i], xb,
                NT, C, 4 * C, 0);
        }
    }
}

// Round 7
// 1132.457 us; speedup vs baseline: 7.3963x; 2.1372x over previous
//
#include <hip/hip_runtime.h>
#include <hip/hip_bf16.h>

// Block_ViT on MI355X — round 7: all GEMMs on bf16 MFMA (16x16x32), batch-fused.
// B=4, N=784, H=4, Cs={64,128,256,512}, KV=960. fp32 in/out, bf16 internals, ~95.6 MB ws.

using bf16 = __hip_bfloat16;
typedef __attribute__((ext_vector_type(8))) short short8;   // 8 bf16 (4 VGPRs)
typedef __attribute__((ext_vector_type(4))) float f32x4;    // MFMA acc

__device__ inline float bf2f(unsigned short u) {
    return __uint_as_float(((unsigned int)u) << 16);
}
__device__ inline unsigned short f2b(float f) {            // RTNE fp32->bf16
    unsigned int u = __float_as_uint(f);
    return (unsigned short)((u + 0x7fffu + ((u >> 16) & 1u)) >> 16);
}
__device__ inline float ld1f(const float* p) { return *p; }
__device__ inline float ld1f(const bf16* p) { return bf2f(*(const unsigned short*)p); }
__device__ inline void st1(float* p, float v) { *p = v; }
__device__ inline void st1(bf16* p, float v) { *((unsigned short*)p) = f2b(v); }
__device__ inline float4 ld4f(const bf16* p) {
    ushort4 u = *(const ushort4*)p;
    return make_float4(bf2f(u.x), bf2f(u.y), bf2f(u.z), bf2f(u.w));
}

// ---- block reductions (256 threads = 4 waves) ----
__device__ inline float blockSum256(float v, float* red) {
    #pragma unroll
    for (int o = 32; o > 0; o >>= 1) v += __shfl_down(v, o);
    int t = threadIdx.x;
    if ((t & 63) == 0) red[t >> 6] = v;
    __syncthreads();
    float r = red[0] + red[1] + red[2] + red[3];
    __syncthreads();
    return r;
}
__device__ inline float blockMax256(float v, float* red) {
    #pragma unroll
    for (int o = 32; o > 0; o >>= 1) v = fmaxf(v, __shfl_down(v, o));
    int t = threadIdx.x;
    if ((t & 63) == 0) red[t >> 6] = v;
    __syncthreads();
    float r = fmaxf(fmaxf(red[0], red[1]), fmaxf(red[2], red[3]));
    __syncthreads();
    return r;
}

// ==== generic MFMA NT GEMM ====
// C[z][M,N] = alpha*A[z][M,K]@B[z][N,K]^T (+bias)(+gelu)(+res)
// A bf16 (lda), B bf16 or fp32 (ldb; fp32 converted in staging), out CT (ldc).
// z-offsets: off = (z&3)*Xh + (z>>2)*Xb.  TO=true: store C^T at [n*ldc + m] (bf16 only).
// Block: 256 thr = 4 waves; tile 128(M) x 64(N) x 32(K); wave w = rows [32w,32w+32).
// Requires N%64==0, K%8==0; M,K guarded (zero-pad).
template <class BT, class CT, bool TO>
__global__ __launch_bounds__(256)
void mfma_nt(const bf16* __restrict__ A, long Ah, long Ab, int lda,
             const BT* __restrict__ B, long Bh, long Bb, int ldb,
             CT* __restrict__ Cp, long Ch, long Cb, int ldc,
             const float* __restrict__ bias, const float* __restrict__ res,
             int M, int N, int K, float alpha, int dogelu) {
    __shared__ short As[128 * 40];   // +8 pad breaks frag-read bank conflicts
    __shared__ short Bs[64 * 40];
    int z = blockIdx.z;
    A += (long)(z & 3) * Ah + (long)(z >> 2) * Ab;
    B += (long)(z & 3) * Bh + (long)(z >> 2) * Bb;
    Cp += (long)(z & 3) * Ch + (long)(z >> 2) * Cb;
    int m0 = blockIdx.y * 128, n0 = blockIdx.x * 64;
    int t = threadIdx.x;
    int lane = t & 63, wv = t >> 6;
    int col = lane & 15, quad = lane >> 4;
    f32x4 acc[2][4];
    #pragma unroll
    for (int i = 0; i < 2; i++)
        #pragma unroll
        for (int j = 0; j < 4; j++) acc[i][j] = (f32x4){0.f, 0.f, 0.f, 0.f};

    const int nsteps = (K + 31) >> 5;
    for (int s = 0; s < nsteps; s++) {
        int k0 = s << 5;
        // stage A tile 128x32 (2x16B per thread)
        #pragma unroll
        for (int u = 0; u < 2; u++) {
            int idx = t + u * 256;
            int r = idx >> 2, cs = (idx & 3) << 3;
            float4 v = make_float4(0.f, 0.f, 0.f, 0.f);
            if (m0 + r < M && k0 + cs < K)
                v = *(const float4*)(A + (long)(m0 + r) * lda + k0 + cs);
            *(float4*)&As[r * 40 + cs] = v;
        }
        // stage B tile 64x32
        {
            int r = t >> 2, cs = (t & 3) << 3;
            if constexpr (sizeof(BT) == 2) {
                float4 v = make_float4(0.f, 0.f, 0.f, 0.f);
                if (k0 + cs < K)
                    v = *(const float4*)((const bf16*)B + (long)(n0 + r) * ldb + k0 + cs);
                *(float4*)&Bs[r * 40 + cs] = v;
            } else {
                ushort4 w0 = make_ushort4(0, 0, 0, 0), w1 = w0;
                if (k0 + cs < K) {
                    const float* bp = (const float*)B + (long)(n0 + r) * ldb + k0 + cs;
                    float4 v0 = *(const float4*)bp;
                    float4 v1 = *(const float4*)(bp + 4);
                    w0 = make_ushort4(f2b(v0.x), f2b(v0.y), f2b(v0.z), f2b(v0.w));
                    w1 = make_ushort4(f2b(v1.x), f2b(v1.y), f2b(v1.z), f2b(v1.w));
                }
                *(ushort4*)&Bs[r * 40 + cs] = w0;
                *(ushort4*)&Bs[r * 40 + cs + 4] = w1;
            }
        }
        __syncthreads();
        short8 a0 = *(const short8*)&As[(wv * 32 + col) * 40 + quad * 8];
        short8 a1 = *(const short8*)&As[(wv * 32 + 16 + col) * 40 + quad * 8];
        short8 b0 = *(const short8*)&Bs[(col) * 40 + quad * 8];
        short8 b1 = *(const short8*)&Bs[(16 + col) * 40 + quad * 8];
        short8 b2 = *(const short8*)&Bs[(32 + col) * 40 + quad * 8];
        short8 b3 = *(const short8*)&Bs[(48 + col) * 40 + quad * 8];
        acc[0][0] = __builtin_amdgcn_mfma_f32_16x16x32_bf16(a0, b0, acc[0][0], 0, 0, 0);
        acc[0][1] = __builtin_amdgcn_mfma_f32_16x16x32_bf16(a0, b1, acc[0][1], 0, 0, 0);
        acc[0][2] = __builtin_amdgcn_mfma_f32_16x16x32_bf16(a0, b2, acc[0][2], 0, 0, 0);
        acc[0][3] = __builtin_amdgcn_mfma_f32_16x16x32_bf16(a0, b3, acc[0][3], 0, 0, 0);
        acc[1][0] = __builtin_amdgcn_mfma_f32_16x16x32_bf16(a1, b0, acc[1][0], 0, 0, 0);
        acc[1][1] = __builtin_amdgcn_mfma_f32_16x16x32_bf16(a1, b1, acc[1][1], 0, 0, 0);
        acc[1][2] = __builtin_amdgcn_mfma_f32_16x16x32_bf16(a1, b2, acc[1][2], 0, 0, 0);
        acc[1][3] = __builtin_amdgcn_mfma_f32_16x16x32_bf16(a1, b3, acc[1][3], 0, 0, 0);
        __syncthreads();
    }
    // epilogue.  C/D layout: col=lane&15, row=quad*4+reg  [verified m89/m91]
    #pragma unroll
    for (int mi = 0; mi < 2; mi++) {
        int gmB = m0 + wv * 32 + mi * 16 + quad * 4;
        #pragma unroll
        for (int ni = 0; ni < 4; ni++) {
            int gn = n0 + ni * 16 + col;
            if constexpr (TO) {
                if (gmB < M) {
                    ushort4 w = make_ushort4(f2b(acc[mi][ni][0] * alpha),
                                             f2b(acc[mi][ni][1] * alpha),
                                             f2b(acc[mi][ni][2] * alpha),
                                             f2b(acc[mi][ni][3] * alpha));
                    *(ushort4*)((unsigned short*)Cp + (long)gn * ldc + gmB) = w;
                }
            } else {
                float bz = bias ? bias[gn] : 0.f;
                #pragma unroll
                for (int r = 0; r < 4; r++) {
                    int gm = gmB + r;
                    if (gm < M) {
                        float v = acc[mi][ni][r] * alpha + bz;
                        if (dogelu) v = 0.5f * v * (1.f + erff(v * 0.70710678118f));
                        if (res) v += res[(long)gm * ldc + gn];
                        st1(Cp + (long)gm * ldc + gn, v);
                    }
                }
            }
        }
    }
}

// ---- LayerNorm of concat: rows of [3136, 960] fp32 -> bf16 ----
__global__ __launch_bounds__(256)
void ln_concat_kernel(const float* __restrict__ e1, const float* __restrict__ e2,
                      const float* __restrict__ e3, const float* __restrict__ e4,
                      const float* __restrict__ g, const float* __restrict__ b,
                      bf16* __restrict__ ea) {
    __shared__ float x[960];
    __shared__ float red[4];
    long row = blockIdx.x;
    int t = threadIdx.x;
    const float* p1 = e1 + row * 64;
    const float* p2 = e2 + row * 128;
    const float* p3 = e3 + row * 256;
    const float* p4 = e4 + row * 512;
    for (int i = t; i < 64;  i += 256) x[i]       = p1[i];
    for (int i = t; i < 128; i += 256) x[64 + i]  = p2[i];
    for (int i = t; i < 256; i += 256) x[192 + i] = p3[i];
    for (int i = t; i < 512; i += 256) x[448 + i] = p4[i];
    __syncthreads();
    float s = 0.f, q = 0.f;
    for (int i = t; i < 960; i += 256) { float v = x[i]; s += v; q += v * v; }
    float S1 = blockSum256(s, red), S2 = blockSum256(q, red);
    const float inv = 1.f / 960.f;
    float mu = S1 * inv;
    float r = rsqrtf(S2 * inv - mu * mu + 1e-6f);
    for (int i = t; i < 960; i += 256)
        st1(ea + row * 960 + i, (x[i] - mu) * r * g[i] + b[i]);
}

// ---- row LayerNorm: [3136, C] fp32 -> bf16 ----
__global__ __launch_bounds__(256)
void ln_rows_kernel(const float* __restrict__ X, const float* __restrict__ g,
                    const float* __restrict__ b, bf16* __restrict__ Y, int C) {
    __shared__ float x[512];
    __shared__ float red[4];
    long row = blockIdx.x;
    int t = threadIdx.x;
    const float* xr = X + row * C;
    float s = 0.f, q = 0.f;
    for (int i = t; i < C; i += 256) { float v = xr[i]; x[i] = v; s += v; q += v * v; }
    float S1 = blockSum256(s, red), S2 = blockSum256(q, red);
    float mu = S1 / C;
    float r = rsqrtf(S2 / C - mu * mu + 1e-6f);
    for (int i = t; i < C; i += 256)
        st1(Y + row * C + i, (x[i] - mu) * r * g[i] + b[i]);
}

// ---- ctx head-sum: ctx[i] = 0.25*sum_h tmp[h][i] (bf16 in/out) ----
__global__ __launch_bounds__(256)
void ctx_sum_kernel(const bf16* __restrict__ tmp, bf16* __restrict__ ctx, long NTC) {
    long i = ((long)blockIdx.x * 256 + threadIdx.x) * 4;
    float4 a = ld4f(tmp + i);
    float4 b = ld4f(tmp + NTC + i);
    float4 c = ld4f(tmp + 2 * NTC + i);
    float4 d = ld4f(tmp + 3 * NTC + i);
    ushort4 o = make_ushort4(f2b((a.x + b.x + c.x + d.x) * 0.25f),
                             f2b((a.y + b.y + c.y + d.y) * 0.25f),
                             f2b((a.z + b.z + c.z + d.z) * 0.25f),
                             f2b((a.w + b.w + c.w + d.w) * 0.25f));
    *(ushort4*)(ctx + i) = o;
}

// ---- instance-norm two-stage reduce over [z][C*960] bf16 ----
__global__ __launch_bounds__(256)
void inorm_part_kernel(const bf16* __restrict__ S, float2* __restrict__ part, int C) {
    __shared__ float red[4];
    int blk = blockIdx.x;
    int z = blk / 12, p = blk % 12;
    long n = (long)C * 960;
    long chunk = n / 12;
    const ushort4* base = (const ushort4*)((const unsigned short*)S + (long)z * n + p * chunk);
    long c4 = chunk >> 2;
    float s = 0.f, q = 0.f;
    for (long i = threadIdx.x; i < c4; i += 256) {
        ushort4 u = base[i];
        float a = bf2f(u.x), b = bf2f(u.y), c = bf2f(u.z), d = bf2f(u.w);
        s += a + b + c + d;
        q += a * a + b * b + c * c + d * d;
    }
    float S1 = blockSum256(s, red), S2 = blockSum256(q, red);
    if (threadIdx.x == 0) part[blk] = make_float2(S1, S2);
}
__global__ __launch_bounds__(64)
void inorm_fin_kernel(const float2* __restrict__ part, float* __restrict__ rstd,
                      int C, int nz) {
    int t = threadIdx.x;
    if (t < nz) {
        float s = 0.f, q = 0.f;
        for (int j = 0; j < 12; j++) { float2 v = part[t * 12 + j]; s += v.x; q += v.y; }
        float n = (float)C * 960.f;
        float mu = s / n;
        rstd[t] = rsqrtf(q / n - mu * mu + 1e-5f);
    }
}

// ---- softmax over last dim (960); IN mean cancels per row (shift-invariance) ----
__global__ __launch_bounds__(256)
void softmax_kernel(bf16* __restrict__ S, const float* __restrict__ rstd, int C) {
    __shared__ float x[960];
    __shared__ float red[4];
    long r = blockIdx.x;          // [z][d] flattened
    int t = threadIdx.x;
    float rs = rstd[r / C];
    bf16* row = S + r * 960;
    float mx = -3.4e38f;
    for (int i = t; i < 960; i += 256) {
        float v = ld1f(row + i) * rs; x[i] = v; mx = fmaxf(mx, v);
    }
    float M = blockMax256(mx, red);
    float s = 0.f;
    for (int i = t; i < 960; i += 256) { float e = __expf(x[i] - M); x[i] = e; s += e; }
    float Ssum = blockSum256(s, red);
    float inv = 1.f / Ssum;
    for (int i = t; i < 960; i += 256) st1(row + i, x[i] * inv);
}

extern "C" void kernel_launch(void* const* d_in, const int* in_sizes, int n_in,
                              void* d_out, int out_size, void* d_ws, size_t ws_size,
                              hipStream_t stream) {
    (void)in_sizes; (void)n_in; (void)out_size; (void)ws_size;
    const int Cs[4] = {64, 128, 256, 512};
    const float *emb[4], *ang[4], *anb[4], *Wq[4], *Wo[4], *fng[4], *fnb[4], *w1[4], *b1[4], *w2[4], *b2[4];
    for (int i = 0; i < 4; i++) {
        const int base = i * 11;
        emb[i] = (const float*)d_in[base + 0];
        ang[i] = (const float*)d_in[base + 1];
        anb[i] = (const float*)d_in[base + 2];
        Wq[i]  = (const float*)d_in[base + 3];
        Wo[i]  = (const float*)d_in[base + 4];
        fng[i] = (const float*)d_in[base + 5];
        fnb[i] = (const float*)d_in[base + 6];
        w1[i]  = (const float*)d_in[base + 7];
        b1[i]  = (const float*)d_in[base + 8];
        w2[i]  = (const float*)d_in[base + 9];
        b2[i]  = (const float*)d_in[base + 10];
    }
    const float* anAg = (const float*)d_in[44];
    const float* anAb = (const float*)d_in[45];
    const float* Wk   = (const float*)d_in[46];
    const float* Wv   = (const float*)d_in[47];

    const int NT = 3136;           // 4 batches x 784 tokens
    // ws layout (bytes), total ~95.6 MB (R6 confirmed ws >= 102 MB)
    char* wsb = (char*)d_ws;
    bf16*   ea   = (bf16*)(wsb);                    // [3136,960]
    bf16*   KT   = (bf16*)(wsb + 6021120);          // [4][960][3136] transposed K
    bf16*   Vb   = (bf16*)(wsb + 30105600);         // [4][3136][960]
    bf16*   Qb   = (bf16*)(wsb + 54190080);         // QT [4][C][3136] / ctx-tmp / hid
    bf16*   Sb   = (bf16*)(wsb + 67035136);         // [16][C][960]
    bf16*   cxb  = (bf16*)(wsb + 82763776);         // [3136,C] LN out
    float*  xb   = (float*)(wsb + 85975040);        // [3136,C] fp32 residual
    bf16*   ctxb = (bf16*)(wsb + 92397568);         // [3136,C]
    float2* part = (float2*)(wsb + 95608832);       // [192]
    float*  rstd = (float*)(wsb + 95610368);        // [16]

    float* out = (float*)d_out;
    const long ooff[4] = {0, 200704, 602112, 1404928};
    const float scale = 0.03227486121f;  // 1/sqrt(960)

    ln_concat_kernel<<<3136, 256, 0, stream>>>(emb[0], emb[1], emb[2], emb[3], anAg, anAb, ea);
    // KT[h] = (ea @ Wk[h]^T)^T   (transposed store)
    mfma_nt<float, bf16, true><<<dim3(15, 25, 4), 256, 0, stream>>>(
        ea, 0, 0, 960, Wk, 921600, 0, 960, KT, (long)960 * NT, 0, NT,
        nullptr, nullptr, NT, 960, 960, 1.f, 0);
    // V[h] = ea @ Wv[h]^T
    mfma_nt<float, bf16, false><<<dim3(15, 25, 4), 256, 0, stream>>>(
        ea, 0, 0, 960, Wv, 921600, 0, 960, Vb, (long)NT * 960, 0, 960,
        nullptr, nullptr, NT, 960, 960, 1.f, 0);

    for (int i = 0; i < 4; i++) {
        const int C = Cs[i];
        // cx = LN(emb_i) -> bf16
        ln_rows_kernel<<<NT, 256, 0, stream>>>(emb[i], ang[i], anb[i], cxb, C);
        // QT[h] = (cx @ Wq[h]^T)^T
        mfma_nt<float, bf16, true><<<dim3(C / 64, 25, 4), 256, 0, stream>>>(
            cxb, 0, 0, C, Wq[i], (long)C * C, 0, C, Qb, (long)C * NT, 0, NT,
            nullptr, nullptr, NT, C, C, 1.f, 0);
        // S[z=b*4+h] = scale * QT[h][:, b] @ KT[h][:, b]^T   (K-dim = 784 tokens)
        mfma_nt<bf16, bf16, false><<<dim3(15, (C + 127) / 128, 16), 256, 0, stream>>>(
            Qb, (long)C * NT, 784, NT, KT, (long)960 * NT, 784, NT,
            Sb, (long)C * 960, (long)4 * C * 960, 960,
            nullptr, nullptr, C, 960, 784, scale, 0);
        // instance-norm rstd + softmax (in place)
        inorm_part_kernel<<<192, 256, 0, stream>>>(Sb, part, C);
        inorm_fin_kernel<<<1, 64, 0, stream>>>(part, rstd, C, 16);
        softmax_kernel<<<16 * C, 256, 0, stream>>>(Sb, rstd, C);
        // tmp[h][b,n,:] = V[h][b,n,:] @ S[z]^T   (per-head ctx, M=784/z)
        mfma_nt<bf16, bf16, false><<<dim3(C / 64, 7, 16), 256, 0, stream>>>(
            Vb, (long)NT * 960, (long)784 * 960, 960, Sb, (long)C * 960, (long)4 * C * 960, 960,
            Qb, (long)NT * C, (long)784 * C, C,
            nullptr, nullptr, 784, C, 960, 1.f, 0);
        ctx_sum_kernel<<<(int)(((long)NT * C) / 1024), 256, 0, stream>>>(
            Qb, ctxb, (long)NT * C);
        // x = emb + ctx @ Wo^T  (fp32)
        mfma_nt<float, float, false><<<dim3(C / 64, 25, 1), 256, 0, stream>>>(
            ctxb, 0, 0, C, Wo[i], 0, 0, C, xb, 0, 0, C,
            nullptr, emb[i], NT, C, C, 1.f, 0);
        // lnx = LN(x) -> bf16
        ln_rows_kernel<<<NT, 256, 0, stream>>>(xb, fng[i], fnb[i], cxb, C);
        // hid = gelu(lnx @ w1^T + b1) -> bf16
        mfma_nt<float, bf16, false><<<dim3(4 * C / 64, 25, 1), 256, 0, stream>>>(
            cxb, 0, 0, C, w1[i], 0, 0, C, Qb, 0, 0, 4 * C,
            b1[i], nullptr, NT, 4 * C, C, 1.f, 1);
        // out = x + hid @ w2^T + b2  (fp32)
        mfma_nt<float, float, false><<<dim3(C / 64, 25, 1), 256, 0, stream>>>(
            Qb, 0, 0, 4 * C, w2[i], 0, 0, 4 * C, out + ooff[i], 0, 0, C,
            b2[i], xb, NT, C, 4 * C, 1.f, 0);
    }
}

// Round 8
// 1043.139 us; speedup vs baseline: 8.0296x; 1.0856x over previous
//
#include <hip/hip_runtime.h>
#include <hip/hip_bf16.h>

// Block_ViT on MI355X — round 8: bigger MFMA tiles (64x64/wave), bf16 pre-converted
// weights, per-call tile selection for grid occupancy. fp32 in/out. ~99.2 MB ws.
// B=4, N=784, H=4, Cs={64,128,256,512}, KV=960, NT=3136.

using bf16 = __hip_bfloat16;
typedef __attribute__((ext_vector_type(8))) short short8;   // 8 bf16 (4 VGPRs)
typedef __attribute__((ext_vector_type(4))) float f32x4;    // MFMA acc

__device__ inline float bf2f(unsigned short u) {
    return __uint_as_float(((unsigned int)u) << 16);
}
__device__ inline unsigned short f2b(float f) {            // RTNE fp32->bf16
    unsigned int u = __float_as_uint(f);
    return (unsigned short)((u + 0x7fffu + ((u >> 16) & 1u)) >> 16);
}
__device__ inline float ld1f(const float* p) { return *p; }
__device__ inline float ld1f(const bf16* p) { return bf2f(*(const unsigned short*)p); }
__device__ inline void st1(float* p, float v) { *p = v; }
__device__ inline void st1(bf16* p, float v) { *((unsigned short*)p) = f2b(v); }
__device__ inline float4 ld4f(const bf16* p) {
    ushort4 u = *(const ushort4*)p;
    return make_float4(bf2f(u.x), bf2f(u.y), bf2f(u.z), bf2f(u.w));
}

// ---- block reductions (256 threads = 4 waves) ----
__device__ inline float blockSum256(float v, float* red) {
    #pragma unroll
    for (int o = 32; o > 0; o >>= 1) v += __shfl_down(v, o);
    int t = threadIdx.x;
    if ((t & 63) == 0) red[t >> 6] = v;
    __syncthreads();
    float r = red[0] + red[1] + red[2] + red[3];
    __syncthreads();
    return r;
}
__device__ inline float blockMax256(float v, float* red) {
    #pragma unroll
    for (int o = 32; o > 0; o >>= 1) v = fmaxf(v, __shfl_down(v, o));
    int t = threadIdx.x;
    if ((t & 63) == 0) red[t >> 6] = v;
    __syncthreads();
    float r = fmaxf(fmaxf(red[0], red[1]), fmaxf(red[2], red[3]));
    __syncthreads();
    return r;
}

// ---- fp32 -> bf16 weight conversion, up to 4 segments in one launch ----
struct Cvt4 {
    const float* s[4];
    unsigned short* d[4];
    long n[4];
};
__global__ __launch_bounds__(256)
void cvt_kernel(Cvt4 a) {
    long tid = (long)blockIdx.x * 256 + threadIdx.x;
    long stride = (long)gridDim.x * 256;
    for (int g = 0; g < 4; g++) {
        const float* s = a.s[g];
        if (!s) continue;
        unsigned short* d = a.d[g];
        long n = a.n[g];
        for (long i = tid * 4; i < n; i += stride * 4) {
            float4 v = *(const float4*)(s + i);
            *(ushort4*)(d + i) = make_ushort4(f2b(v.x), f2b(v.y), f2b(v.z), f2b(v.w));
        }
    }
}

// ==== MFMA NT GEMM, templated tile ====
// C[z][M,N] = alpha*A[z]@B[z]^T (+bias)(+gelu)(+res). All operands bf16 except
// bias fp32, res RT, out CT. z-offsets: (z&3)*Xh + (z>>2)*Xb.
// TO=true: store C^T (bf16 only) at [n*ldc + m].
// 4 waves as 2x2; wave tile (TM/2)x(TN/2); BK=32. M,N,K guarded (K at 8-granularity).
template <int TM, int TN, class CT, class RT, bool TO>
__global__ __launch_bounds__(256)
void mfma2(const bf16* __restrict__ A, long Ah, long Ab, int lda,
           const bf16* __restrict__ B, long Bh, long Bb, int ldb,
           CT* __restrict__ Cp, long Ch, long Cb, int ldc,
           const float* __restrict__ bias, const RT* __restrict__ res,
           int M, int N, int K, float alpha, int dogelu) {
    constexpr int MI = TM / 32, NI = TN / 32;
    __shared__ short As[TM * 40];   // stride 40 (80B): frag reads land 2-way = free
    __shared__ short Bs[TN * 40];
    int z = blockIdx.z;
    A += (long)(z & 3) * Ah + (long)(z >> 2) * Ab;
    B += (long)(z & 3) * Bh + (long)(z >> 2) * Bb;
    Cp += (long)(z & 3) * Ch + (long)(z >> 2) * Cb;
    int m0 = blockIdx.y * TM, n0 = blockIdx.x * TN;
    int t = threadIdx.x, lane = t & 63, wv = t >> 6;
    int col = lane & 15, quad = lane >> 4;
    int wm = wv >> 1, wn = wv & 1;
    f32x4 acc[MI][NI];
    #pragma unroll
    for (int i = 0; i < MI; i++)
        #pragma unroll
        for (int j = 0; j < NI; j++) acc[i][j] = (f32x4){0.f, 0.f, 0.f, 0.f};

    int sr = t >> 2, scs = (t & 3) << 3;
    for (int k0 = 0; k0 < K; k0 += 32) {
        #pragma unroll
        for (int u = 0; u < TM / 64; u++) {
            int r = sr + u * 64;
            float4 v = make_float4(0.f, 0.f, 0.f, 0.f);
            if (m0 + r < M && k0 + scs < K)
                v = *(const float4*)(A + (long)(m0 + r) * lda + k0 + scs);
            *(float4*)&As[r * 40 + scs] = v;
        }
        #pragma unroll
        for (int u = 0; u < TN / 64; u++) {
            int r = sr + u * 64;
            float4 v = make_float4(0.f, 0.f, 0.f, 0.f);
            if (n0 + r < N && k0 + scs < K)
                v = *(const float4*)(B + (long)(n0 + r) * ldb + k0 + scs);
            *(float4*)&Bs[r * 40 + scs] = v;
        }
        __syncthreads();
        short8 af[MI], bfr[NI];
        #pragma unroll
        for (int mi = 0; mi < MI; mi++)
            af[mi] = *(const short8*)&As[(wm * (TM / 2) + mi * 16 + col) * 40 + quad * 8];
        #pragma unroll
        for (int ni = 0; ni < NI; ni++)
            bfr[ni] = *(const short8*)&Bs[(wn * (TN / 2) + ni * 16 + col) * 40 + quad * 8];
        #pragma unroll
        for (int mi = 0; mi < MI; mi++)
            #pragma unroll
            for (int ni = 0; ni < NI; ni++)
                acc[mi][ni] = __builtin_amdgcn_mfma_f32_16x16x32_bf16(
                    af[mi], bfr[ni], acc[mi][ni], 0, 0, 0);
        __syncthreads();
    }
    // C/D layout: col=lane&15, row=quad*4+reg  [verified m89/m91]
    #pragma unroll
    for (int mi = 0; mi < MI; mi++) {
        int gmB = m0 + wm * (TM / 2) + mi * 16 + quad * 4;
        #pragma unroll
        for (int ni = 0; ni < NI; ni++) {
            int gn = n0 + wn * (TN / 2) + ni * 16 + col;
            if constexpr (TO) {
                if (gmB < M && gn < N) {
                    ushort4 w = make_ushort4(f2b(acc[mi][ni][0] * alpha),
                                             f2b(acc[mi][ni][1] * alpha),
                                             f2b(acc[mi][ni][2] * alpha),
                                             f2b(acc[mi][ni][3] * alpha));
                    *(ushort4*)((unsigned short*)Cp + (long)gn * ldc + gmB) = w;
                }
            } else {
                if (gn < N) {
                    float bz = bias ? bias[gn] : 0.f;
                    #pragma unroll
                    for (int r = 0; r < 4; r++) {
                        int gm = gmB + r;
                        if (gm < M) {
                            float v = acc[mi][ni][r] * alpha + bz;
                            if (dogelu) v = 0.5f * v * (1.f + erff(v * 0.70710678118f));
                            if (res) v += ld1f(res + (long)gm * ldc + gn);
                            st1(Cp + (long)gm * ldc + gn, v);
                        }
                    }
                }
            }
        }
    }
}

// ---- LayerNorm of concat: rows of [3136, 960] fp32 -> bf16 ----
__global__ __launch_bounds__(256)
void ln_concat_kernel(const float* __restrict__ e1, const float* __restrict__ e2,
                      const float* __restrict__ e3, const float* __restrict__ e4,
                      const float* __restrict__ g, const float* __restrict__ b,
                      bf16* __restrict__ ea) {
    __shared__ float x[960];
    __shared__ float red[4];
    long row = blockIdx.x;
    int t = threadIdx.x;
    const float* p1 = e1 + row * 64;
    const float* p2 = e2 + row * 128;
    const float* p3 = e3 + row * 256;
    const float* p4 = e4 + row * 512;
    for (int i = t; i < 64;  i += 256) x[i]       = p1[i];
    for (int i = t; i < 128; i += 256) x[64 + i]  = p2[i];
    for (int i = t; i < 256; i += 256) x[192 + i] = p3[i];
    for (int i = t; i < 512; i += 256) x[448 + i] = p4[i];
    __syncthreads();
    float s = 0.f, q = 0.f;
    for (int i = t; i < 960; i += 256) { float v = x[i]; s += v; q += v * v; }
    float S1 = blockSum256(s, red), S2 = blockSum256(q, red);
    const float inv = 1.f / 960.f;
    float mu = S1 * inv;
    float r = rsqrtf(S2 * inv - mu * mu + 1e-6f);
    for (int i = t; i < 960; i += 256)
        st1(ea + row * 960 + i, (x[i] - mu) * r * g[i] + b[i]);
}

// ---- row LayerNorm: [3136, C] (fp32 or bf16 in) -> bf16 ----
template <class XT>
__global__ __launch_bounds__(256)
void ln_rows_kernel(const XT* __restrict__ X, const float* __restrict__ g,
                    const float* __restrict__ b, bf16* __restrict__ Y, int C) {
    __shared__ float x[512];
    __shared__ float red[4];
    long row = blockIdx.x;
    int t = threadIdx.x;
    const XT* xr = X + row * C;
    float s = 0.f, q = 0.f;
    for (int i = t; i < C; i += 256) { float v = ld1f(xr + i); x[i] = v; s += v; q += v * v; }
    float S1 = blockSum256(s, red), S2 = blockSum256(q, red);
    float mu = S1 / C;
    float r = rsqrtf(S2 / C - mu * mu + 1e-6f);
    for (int i = t; i < C; i += 256)
        st1(Y + row * C + i, (x[i] - mu) * r * g[i] + b[i]);
}

// ---- ctx head-sum: ctx[i] = 0.25*sum_h tmp[h][i] (bf16 in/out) ----
__global__ __launch_bounds__(256)
void ctx_sum_kernel(const bf16* __restrict__ tmp, bf16* __restrict__ ctx, long NTC) {
    long i = ((long)blockIdx.x * 256 + threadIdx.x) * 4;
    float4 a = ld4f(tmp + i);
    float4 b = ld4f(tmp + NTC + i);
    float4 c = ld4f(tmp + 2 * NTC + i);
    float4 d = ld4f(tmp + 3 * NTC + i);
    ushort4 o = make_ushort4(f2b((a.x + b.x + c.x + d.x) * 0.25f),
                             f2b((a.y + b.y + c.y + d.y) * 0.25f),
                             f2b((a.z + b.z + c.z + d.z) * 0.25f),
                             f2b((a.w + b.w + c.w + d.w) * 0.25f));
    *(ushort4*)(ctx + i) = o;
}

// ---- instance-norm two-stage reduce over [z][C*960] bf16 ----
__global__ __launch_bounds__(256)
void inorm_part_kernel(const bf16* __restrict__ S, float2* __restrict__ part, int C) {
    __shared__ float red[4];
    int blk = blockIdx.x;
    int z = blk / 12, p = blk % 12;
    long n = (long)C * 960;
    long chunk = n / 12;
    const ushort4* base = (const ushort4*)((const unsigned short*)S + (long)z * n + p * chunk);
    long c4 = chunk >> 2;
    float s = 0.f, q = 0.f;
    for (long i = threadIdx.x; i < c4; i += 256) {
        ushort4 u = base[i];
        float a = bf2f(u.x), b = bf2f(u.y), c = bf2f(u.z), d = bf2f(u.w);
        s += a + b + c + d;
        q += a * a + b * b + c * c + d * d;
    }
    float S1 = blockSum256(s, red), S2 = blockSum256(q, red);
    if (threadIdx.x == 0) part[blk] = make_float2(S1, S2);
}
__global__ __launch_bounds__(64)
void inorm_fin_kernel(const float2* __restrict__ part, float* __restrict__ rstd,
                      int C, int nz) {
    int t = threadIdx.x;
    if (t < nz) {
        float s = 0.f, q = 0.f;
        for (int j = 0; j < 12; j++) { float2 v = part[t * 12 + j]; s += v.x; q += v.y; }
        float n = (float)C * 960.f;
        float mu = s / n;
        rstd[t] = rsqrtf(q / n - mu * mu + 1e-5f);
    }
}

// ---- softmax over last dim (960); IN mean cancels per row (shift-invariance) ----
__global__ __launch_bounds__(256)
void softmax_kernel(bf16* __restrict__ S, const float* __restrict__ rstd, int C) {
    __shared__ float x[960];
    __shared__ float red[4];
    long r = blockIdx.x;
    int t = threadIdx.x;
    float rs = rstd[r / C];
    bf16* row = S + r * 960;
    float mx = -3.4e38f;
    for (int i = t; i < 960; i += 256) {
        float v = ld1f(row + i) * rs; x[i] = v; mx = fmaxf(mx, v);
    }
    float M = blockMax256(mx, red);
    float s = 0.f;
    for (int i = t; i < 960; i += 256) { float e = __expf(x[i] - M); x[i] = e; s += e; }
    float Ssum = blockSum256(s, red);
    float inv = 1.f / Ssum;
    for (int i = t; i < 960; i += 256) st1(row + i, x[i] * inv);
}

extern "C" void kernel_launch(void* const* d_in, const int* in_sizes, int n_in,
                              void* d_out, int out_size, void* d_ws, size_t ws_size,
                              hipStream_t stream) {
    (void)in_sizes; (void)n_in; (void)out_size; (void)ws_size;
    const int Cs[4] = {64, 128, 256, 512};
    const float *emb[4], *ang[4], *anb[4], *Wq[4], *Wo[4], *fng[4], *fnb[4], *w1[4], *b1[4], *w2[4], *b2[4];
    for (int i = 0; i < 4; i++) {
        const int base = i * 11;
        emb[i] = (const float*)d_in[base + 0];
        ang[i] = (const float*)d_in[base + 1];
        anb[i] = (const float*)d_in[base + 2];
        Wq[i]  = (const float*)d_in[base + 3];
        Wo[i]  = (const float*)d_in[base + 4];
        fng[i] = (const float*)d_in[base + 5];
        fnb[i] = (const float*)d_in[base + 6];
        w1[i]  = (const float*)d_in[base + 7];
        b1[i]  = (const float*)d_in[base + 8];
        w2[i]  = (const float*)d_in[base + 9];
        b2[i]  = (const float*)d_in[base + 10];
    }
    const float* anAg = (const float*)d_in[44];
    const float* anAb = (const float*)d_in[45];
    const float* Wk   = (const float*)d_in[46];
    const float* Wv   = (const float*)d_in[47];

    const int NT = 3136;
    // ws layout (bytes), ~99.2 MB (ws_size >= 102.2 MB verified in R6)
    char* wsb = (char*)d_ws;
    bf16*   ea   = (bf16*)(wsb);                    // [3136,960]
    bf16*   KT   = (bf16*)(wsb + 6021120);          // [4][960][3136] K^T
    bf16*   Vb   = (bf16*)(wsb + 30105600);         // [4][3136][960]
    bf16*   Qb   = (bf16*)(wsb + 54190080);         // QT [4][C][3136] / ctx tmp / hid
    bf16*   Sb   = (bf16*)(wsb + 67035136);         // [16][C][960]; also Wk/Wv bf16 early
    bf16*   cxb  = (bf16*)(wsb + 82763776);         // [3136,C] LN out
    bf16*   xb   = (bf16*)(wsb + 85975040);         // [3136,C] residual
    bf16*   ctxb = (bf16*)(wsb + 89186304);         // [3136,C]
    bf16*   wtb  = (bf16*)(wsb + 92397568);         // branch weights bf16 (<=6.82 MB)
    float2* part = (float2*)(wsb + 99213312);       // [192]
    float*  rstd = (float*)(wsb + 99214848);        // [16]

    bf16* wkb = Sb;                 // Wk bf16 (3,686,400 elems) — Sb free until scores
    bf16* wvb = Sb + 3686400;       // Wv bf16

    float* out = (float*)d_out;
    const long ooff[4] = {0, 200704, 602112, 1404928};
    const float scale = 0.03227486121f;  // 1/sqrt(960)

    // weights Wk/Wv -> bf16
    {
        Cvt4 a;
        a.s[0] = Wk; a.d[0] = (unsigned short*)wkb; a.n[0] = 3686400;
        a.s[1] = Wv; a.d[1] = (unsigned short*)wvb; a.n[1] = 3686400;
        a.s[2] = nullptr; a.s[3] = nullptr; a.d[2] = a.d[3] = nullptr; a.n[2] = a.n[3] = 0;
        cvt_kernel<<<512, 256, 0, stream>>>(a);
    }
    ln_concat_kernel<<<3136, 256, 0, stream>>>(emb[0], emb[1], emb[2], emb[3], anAg, anAb, ea);
    // KT[h] = (ea @ Wk[h]^T)^T
    mfma2<128, 128, bf16, float, true><<<dim3(8, 25, 4), 256, 0, stream>>>(
        ea, 0, 0, 960, wkb, 921600, 0, 960, KT, 3010560, 0, NT,
        nullptr, (const float*)nullptr, NT, 960, 960, 1.f, 0);
    // V[h] = ea @ Wv[h]^T
    mfma2<128, 128, bf16, float, false><<<dim3(8, 25, 4), 256, 0, stream>>>(
        ea, 0, 0, 960, wvb, 921600, 0, 960, Vb, 3010560, 0, 960,
        nullptr, (const float*)nullptr, NT, 960, 960, 1.f, 0);

    for (int i = 0; i < 4; i++) {
        const int C = Cs[i];
        const long C2 = (long)C * C;
        bf16* wqb = wtb;
        bf16* wob = wtb + 4 * C2;
        bf16* w1b = wtb + 5 * C2;
        bf16* w2b = wtb + 9 * C2;
        {
            Cvt4 a;
            a.s[0] = Wq[i]; a.d[0] = (unsigned short*)wqb; a.n[0] = 4 * C2;
            a.s[1] = Wo[i]; a.d[1] = (unsigned short*)wob; a.n[1] = C2;
            a.s[2] = w1[i]; a.d[2] = (unsigned short*)w1b; a.n[2] = 4 * C2;
            a.s[3] = w2[i]; a.d[3] = (unsigned short*)w2b; a.n[3] = 4 * C2;
            cvt_kernel<<<512, 256, 0, stream>>>(a);
        }
        // cx = LN(emb_i) -> bf16
        ln_rows_kernel<float><<<NT, 256, 0, stream>>>(emb[i], ang[i], anb[i], cxb, C);
        // QT[h] = (cx @ Wq[h]^T)^T
        mfma2<64, 64, bf16, float, true><<<dim3(C / 64, 49, 4), 256, 0, stream>>>(
            cxb, 0, 0, C, wqb, C2, 0, C, Qb, (long)C * NT, 0, NT,
            nullptr, (const float*)nullptr, NT, C, C, 1.f, 0);
        // S[z] = scale * QT-slab @ KT-slab^T  (M=C, N=960, K=784)
        if (C >= 256)
            mfma2<128, 128, bf16, float, false><<<dim3(8, C / 128, 16), 256, 0, stream>>>(
                Qb, (long)C * NT, 784, NT, KT, 3010560, 784, NT,
                Sb, (long)C * 960, (long)4 * C * 960, 960,
                nullptr, (const float*)nullptr, C, 960, 784, scale, 0);
        else
            mfma2<64, 64, bf16, float, false><<<dim3(15, C / 64, 16), 256, 0, stream>>>(
                Qb, (long)C * NT, 784, NT, KT, 3010560, 784, NT,
                Sb, (long)C * 960, (long)4 * C * 960, 960,
                nullptr, (const float*)nullptr, C, 960, 784, scale, 0);
        // instance-norm rstd + softmax (in place)
        inorm_part_kernel<<<192, 256, 0, stream>>>(Sb, part, C);
        inorm_fin_kernel<<<1, 64, 0, stream>>>(part, rstd, C, 16);
        softmax_kernel<<<16 * C, 256, 0, stream>>>(Sb, rstd, C);
        // tmp[h] = V-slab @ S[z]^T  (M=784, N=C, K=960)
        if (C == 512)
            mfma2<128, 128, bf16, float, false><<<dim3(C / 128, 7, 16), 256, 0, stream>>>(
                Vb, 3010560, 784L * 960, 960, Sb, (long)C * 960, (long)4 * C * 960, 960,
                Qb, (long)NT * C, 784L * C, C,
                nullptr, (const float*)nullptr, 784, C, 960, 1.f, 0);
        else
            mfma2<64, 64, bf16, float, false><<<dim3(C / 64, 13, 16), 256, 0, stream>>>(
                Vb, 3010560, 784L * 960, 960, Sb, (long)C * 960, (long)4 * C * 960, 960,
                Qb, (long)NT * C, 784L * C, C,
                nullptr, (const float*)nullptr, 784, C, 960, 1.f, 0);
        ctx_sum_kernel<<<(int)(((long)NT * C) / 1024), 256, 0, stream>>>(
            Qb, ctxb, (long)NT * C);
        // x = emb + ctx @ Wo^T  -> bf16
        mfma2<64, 64, bf16, float, false><<<dim3(C / 64, 49, 1), 256, 0, stream>>>(
            ctxb, 0, 0, C, wob, 0, 0, C, xb, 0, 0, C,
            nullptr, emb[i], NT, C, C, 1.f, 0);
        // lnx = LN(x) -> bf16
        ln_rows_kernel<bf16><<<NT, 256, 0, stream>>>(xb, fng[i], fnb[i], cxb, C);
        // hid = gelu(lnx @ w1^T + b1) -> bf16
        if (C == 512)
            mfma2<128, 128, bf16, float, false><<<dim3(16, 25, 1), 256, 0, stream>>>(
                cxb, 0, 0, C, w1b, 0, 0, C, Qb, 0, 0, 4 * C,
                b1[i], (const float*)nullptr, NT, 4 * C, C, 1.f, 1);
        else
            mfma2<64, 64, bf16, float, false><<<dim3(4 * C / 64, 49, 1), 256, 0, stream>>>(
                cxb, 0, 0, C, w1b, 0, 0, C, Qb, 0, 0, 4 * C,
                b1[i], (const float*)nullptr, NT, 4 * C, C, 1.f, 1);
        // out = x + hid @ w2^T + b2  (fp32 store to d_out)
        mfma2<64, 64, float, bf16, false><<<dim3(C / 64, 49, 1), 256, 0, stream>>>(
            Qb, 0, 0, 4 * C, w2b, 0, 0, 4 * C, out + ooff[i], 0, 0, C,
            b2[i], xb, NT, C, 4 * C, 1.f, 0);
    }
}

// Round 12
// 951.467 us; speedup vs baseline: 8.8033x; 1.0963x over previous
//
#include <hip/hip_runtime.h>
#include <hip/hip_bf16.h>

// Block_ViT on MI355X — round 12: fix weight-packing bug (R9 wcum used 9C² stride
// for 13C² payload → racing overlapped cvt writes). Per-branch cvt into reused wtb
// (R8-proven). Async global_load_lds staging everywhere. LN4 + batched wk/wv cvt kept.
// B=4, N=784, H=4, Cs={64,128,256,512}, KV=960, NT=3136. fp32 in/out. ~102.0 MB ws.

using bf16 = __hip_bfloat16;
typedef __attribute__((ext_vector_type(8))) short short8;   // 8 bf16 (4 VGPRs)
typedef __attribute__((ext_vector_type(4))) float f32x4;    // MFMA acc

__device__ inline float bf2f(unsigned short u) {
    return __uint_as_float(((unsigned int)u) << 16);
}
__device__ inline unsigned short f2b(float f) {            // RTNE fp32->bf16
    unsigned int u = __float_as_uint(f);
    return (unsigned short)((u + 0x7fffu + ((u >> 16) & 1u)) >> 16);
}
__device__ inline float ld1f(const float* p) { return *p; }
__device__ inline float ld1f(const bf16* p) { return bf2f(*(const unsigned short*)p); }
__device__ inline void st1(float* p, float v) { *p = v; }
__device__ inline void st1(bf16* p, float v) { *((unsigned short*)p) = f2b(v); }
__device__ inline float4 ld4f(const bf16* p) {
    ushort4 u = *(const ushort4*)p;
    return make_float4(bf2f(u.x), bf2f(u.y), bf2f(u.z), bf2f(u.w));
}

// async global->LDS, 16 B per lane; LDS dest = wave-uniform base + lane*16
__device__ __forceinline__ void cp16(const void* g, void* l) {
    __builtin_amdgcn_global_load_lds(
        (const __attribute__((address_space(1))) void*)g,
        (__attribute__((address_space(3))) void*)l, 16, 0, 0);
}

// ---- block reductions (256 threads = 4 waves) ----
__device__ inline float blockSum256(float v, float* red) {
    #pragma unroll
    for (int o = 32; o > 0; o >>= 1) v += __shfl_down(v, o);
    int t = threadIdx.x;
    if ((t & 63) == 0) red[t >> 6] = v;
    __syncthreads();
    float r = red[0] + red[1] + red[2] + red[3];
    __syncthreads();
    return r;
}
__device__ inline float blockMax256(float v, float* red) {
    #pragma unroll
    for (int o = 32; o > 0; o >>= 1) v = fmaxf(v, __shfl_down(v, o));
    int t = threadIdx.x;
    if ((t & 63) == 0) red[t >> 6] = v;
    __syncthreads();
    float r = fmaxf(fmaxf(red[0], red[1]), fmaxf(red[2], red[3]));
    __syncthreads();
    return r;
}

// ---- fp32 -> bf16 weight conversion, up to 4 DISJOINT segments, grid-stride ----
struct Cvt4 {
    const float* s[4];
    unsigned short* d[4];
    long n[4];
};
__global__ __launch_bounds__(256)
void cvt_kernel(Cvt4 a) {
    long tid = (long)blockIdx.x * 256 + threadIdx.x;
    long stride = (long)gridDim.x * 256;
    for (int g = 0; g < 4; g++) {
        const float* s = a.s[g];
        if (!s) continue;
        unsigned short* d = a.d[g];
        long n = a.n[g];
        for (long i = tid * 4; i < n; i += stride * 4) {
            float4 v = *(const float4*)(s + i);
            *(ushort4*)(d + i) = make_ushort4(f2b(v.x), f2b(v.y), f2b(v.z), f2b(v.w));
        }
    }
}

// ==== MFMA NT GEMM with global_load_lds async staging ====
// C[z][M,N] = alpha*A[z]@B[z]^T (+bias)(+gelu)(+res); bf16 A/B, out CT.
// z-offsets: (z&3)*Xh + (z>>2)*Xb. TO: store C^T (bf16).
// 4 waves 2x2, wave tile (TM/2)x(TN/2), BK=32, LDS stride 32 shorts.
template <int TM, int TN, class CT, class RT, bool TO>
__global__ __launch_bounds__(256)
void mfma2(const bf16* __restrict__ A, long Ah, long Ab, int lda,
           const bf16* __restrict__ B, long Bh, long Bb, int ldb,
           CT* __restrict__ Cp, long Ch, long Cb, int ldc,
           const float* __restrict__ bias, const RT* __restrict__ res,
           int M, int N, int K, float alpha, int dogelu) {
    constexpr int MI = TM / 32, NI = TN / 32;
    __shared__ short As[TM * 32];
    __shared__ short Bs[TN * 32];
    int z = blockIdx.z;
    A += (long)(z & 3) * Ah + (long)(z >> 2) * Ab;
    B += (long)(z & 3) * Bh + (long)(z >> 2) * Bb;
    Cp += (long)(z & 3) * Ch + (long)(z >> 2) * Cb;
    int m0 = blockIdx.y * TM, n0 = blockIdx.x * TN;
    int t = threadIdx.x, lane = t & 63, wv = t >> 6;
    int col = lane & 15, quad = lane >> 4;
    int wm = wv >> 1, wn = wv & 1;
    f32x4 acc[MI][NI];
    #pragma unroll
    for (int i = 0; i < MI; i++)
        #pragma unroll
        for (int j = 0; j < NI; j++) acc[i][j] = (f32x4){0.f, 0.f, 0.f, 0.f};

    const bool fastblk = (m0 + TM <= M) && (n0 + TN <= N);
    int lrow = lane >> 2, lcol = (lane & 3) << 3;   // async per-lane row/col
    int sr = t >> 2, scs = (t & 3) << 3;            // manual path row/col

    for (int k0 = 0; k0 < K; k0 += 32) {
        if (fastblk && (k0 + 32 <= K)) {
            #pragma unroll
            for (int u = 0; u < TM / 64; u++) {
                int c = wv + 4 * u;
                int r = c * 16 + lrow;
                cp16(A + (long)(m0 + r) * lda + k0 + lcol, &As[c * 512]);
            }
            #pragma unroll
            for (int u = 0; u < TN / 64; u++) {
                int c = wv + 4 * u;
                int r = c * 16 + lrow;
                cp16(B + (long)(n0 + r) * ldb + k0 + lcol, &Bs[c * 512]);
            }
        } else {
            #pragma unroll
            for (int u = 0; u < TM / 64; u++) {
                int r = sr + u * 64;
                float4 v = make_float4(0.f, 0.f, 0.f, 0.f);
                if (m0 + r < M && k0 + scs < K)
                    v = *(const float4*)(A + (long)(m0 + r) * lda + k0 + scs);
                *(float4*)&As[r * 32 + scs] = v;
            }
            #pragma unroll
            for (int u = 0; u < TN / 64; u++) {
                int r = sr + u * 64;
                float4 v = make_float4(0.f, 0.f, 0.f, 0.f);
                if (n0 + r < N && k0 + scs < K)
                    v = *(const float4*)(B + (long)(n0 + r) * ldb + k0 + scs);
                *(float4*)&Bs[r * 32 + scs] = v;
            }
        }
        __syncthreads();
        short8 af[MI], bfr[NI];
        #pragma unroll
        for (int mi = 0; mi < MI; mi++)
            af[mi] = *(const short8*)&As[(wm * (TM / 2) + mi * 16 + col) * 32 + quad * 8];
        #pragma unroll
        for (int ni = 0; ni < NI; ni++)
            bfr[ni] = *(const short8*)&Bs[(wn * (TN / 2) + ni * 16 + col) * 32 + quad * 8];
        #pragma unroll
        for (int mi = 0; mi < MI; mi++)
            #pragma unroll
            for (int ni = 0; ni < NI; ni++)
                acc[mi][ni] = __builtin_amdgcn_mfma_f32_16x16x32_bf16(
                    af[mi], bfr[ni], acc[mi][ni], 0, 0, 0);
        __syncthreads();
    }
    // C/D layout: col=lane&15, row=quad*4+reg  [m89/m91]
    #pragma unroll
    for (int mi = 0; mi < MI; mi++) {
        int gmB = m0 + wm * (TM / 2) + mi * 16 + quad * 4;
        #pragma unroll
        for (int ni = 0; ni < NI; ni++) {
            int gn = n0 + wn * (TN / 2) + ni * 16 + col;
            if constexpr (TO) {
                if (gmB < M && gn < N) {
                    ushort4 w = make_ushort4(f2b(acc[mi][ni][0] * alpha),
                                             f2b(acc[mi][ni][1] * alpha),
                                             f2b(acc[mi][ni][2] * alpha),
                                             f2b(acc[mi][ni][3] * alpha));
                    *(ushort4*)((unsigned short*)Cp + (long)gn * ldc + gmB) = w;
                }
            } else {
                if (gn < N) {
                    float bz = bias ? bias[gn] : 0.f;
                    #pragma unroll
                    for (int r = 0; r < 4; r++) {
                        int gm = gmB + r;
                        if (gm < M) {
                            float v = acc[mi][ni][r] * alpha + bz;
                            if (dogelu) v = 0.5f * v * (1.f + erff(v * 0.70710678118f));
                            if (res) v += ld1f(res + (long)gm * ldc + gn);
                            st1(Cp + (long)gm * ldc + gn, v);
                        }
                    }
                }
            }
        }
    }
}

// ---- LayerNorm of concat: rows of [3136, 960] fp32 -> bf16 ----
__global__ __launch_bounds__(256)
void ln_concat_kernel(const float* __restrict__ e1, const float* __restrict__ e2,
                      const float* __restrict__ e3, const float* __restrict__ e4,
                      const float* __restrict__ g, const float* __restrict__ b,
                      bf16* __restrict__ ea) {
    __shared__ float x[960];
    __shared__ float red[4];
    long row = blockIdx.x;
    int t = threadIdx.x;
    const float* p1 = e1 + row * 64;
    const float* p2 = e2 + row * 128;
    const float* p3 = e3 + row * 256;
    const float* p4 = e4 + row * 512;
    for (int i = t; i < 64;  i += 256) x[i]       = p1[i];
    for (int i = t; i < 128; i += 256) x[64 + i]  = p2[i];
    for (int i = t; i < 256; i += 256) x[192 + i] = p3[i];
    for (int i = t; i < 512; i += 256) x[448 + i] = p4[i];
    __syncthreads();
    float s = 0.f, q = 0.f;
    for (int i = t; i < 960; i += 256) { float v = x[i]; s += v; q += v * v; }
    float S1 = blockSum256(s, red), S2 = blockSum256(q, red);
    const float inv = 1.f / 960.f;
    float mu = S1 * inv;
    float r = rsqrtf(S2 * inv - mu * mu + 1e-6f);
    for (int i = t; i < 960; i += 256)
        st1(ea + row * 960 + i, (x[i] - mu) * r * g[i] + b[i]);
}

// ---- batched first-LN of all 4 branches: grid (3136, 4) ----
struct LN4 {
    const float* x[4];
    const float* g[4];
    const float* b[4];
    bf16* y[4];
    int C[4];
};
__global__ __launch_bounds__(256)
void ln4_kernel(LN4 a) {
    __shared__ float x[512];
    __shared__ float red[4];
    int br = blockIdx.y;
    long row = blockIdx.x;
    int C = a.C[br];
    int t = threadIdx.x;
    const float* xr = a.x[br] + row * C;
    float s = 0.f, q = 0.f;
    for (int i = t; i < C; i += 256) { float v = xr[i]; x[i] = v; s += v; q += v * v; }
    float S1 = blockSum256(s, red), S2 = blockSum256(q, red);
    float mu = S1 / C;
    float r = rsqrtf(S2 / C - mu * mu + 1e-6f);
    const float* g = a.g[br];
    const float* b = a.b[br];
    bf16* y = a.y[br] + row * C;
    for (int i = t; i < C; i += 256) st1(y + i, (x[i] - mu) * r * g[i] + b[i]);
}

// ---- row LayerNorm (bf16 in) -> bf16 ----
__global__ __launch_bounds__(256)
void ln_rows_kernel(const bf16* __restrict__ X, const float* __restrict__ g,
                    const float* __restrict__ b, bf16* __restrict__ Y, int C) {
    __shared__ float x[512];
    __shared__ float red[4];
    long row = blockIdx.x;
    int t = threadIdx.x;
    const bf16* xr = X + row * C;
    float s = 0.f, q = 0.f;
    for (int i = t; i < C; i += 256) { float v = ld1f(xr + i); x[i] = v; s += v; q += v * v; }
    float S1 = blockSum256(s, red), S2 = blockSum256(q, red);
    float mu = S1 / C;
    float r = rsqrtf(S2 / C - mu * mu + 1e-6f);
    for (int i = t; i < C; i += 256)
        st1(Y + row * C + i, (x[i] - mu) * r * g[i] + b[i]);
}

// ---- ctx head-sum: ctx[i] = 0.25*sum_h tmp[h][i] ----
__global__ __launch_bounds__(256)
void ctx_sum_kernel(const bf16* __restrict__ tmp, bf16* __restrict__ ctx, long NTC) {
    long i = ((long)blockIdx.x * 256 + threadIdx.x) * 4;
    float4 a = ld4f(tmp + i);
    float4 b = ld4f(tmp + NTC + i);
    float4 c = ld4f(tmp + 2 * NTC + i);
    float4 d = ld4f(tmp + 3 * NTC + i);
    ushort4 o = make_ushort4(f2b((a.x + b.x + c.x + d.x) * 0.25f),
                             f2b((a.y + b.y + c.y + d.y) * 0.25f),
                             f2b((a.z + b.z + c.z + d.z) * 0.25f),
                             f2b((a.w + b.w + c.w + d.w) * 0.25f));
    *(ushort4*)(ctx + i) = o;
}

// ---- instance-norm two-stage reduce over [z][C*960] bf16 ----
__global__ __launch_bounds__(256)
void inorm_part_kernel(const bf16* __restrict__ S, float2* __restrict__ part, int C) {
    __shared__ float red[4];
    int blk = blockIdx.x;
    int z = blk / 12, p = blk % 12;
    long n = (long)C * 960;
    long chunk = n / 12;
    const ushort4* base = (const ushort4*)((const unsigned short*)S + (long)z * n + p * chunk);
    long c4 = chunk >> 2;
    float s = 0.f, q = 0.f;
    for (long i = threadIdx.x; i < c4; i += 256) {
        ushort4 u = base[i];
        float a = bf2f(u.x), b = bf2f(u.y), c = bf2f(u.z), d = bf2f(u.w);
        s += a + b + c + d;
        q += a * a + b * b + c * c + d * d;
    }
    float S1 = blockSum256(s, red), S2 = blockSum256(q, red);
    if (threadIdx.x == 0) part[blk] = make_float2(S1, S2);
}
__global__ __launch_bounds__(64)
void inorm_fin_kernel(const float2* __restrict__ part, float* __restrict__ rstd,
                      int C, int nz) {
    int t = threadIdx.x;
    if (t < nz) {
        float s = 0.f, q = 0.f;
        for (int j = 0; j < 12; j++) { float2 v = part[t * 12 + j]; s += v.x; q += v.y; }
        float n = (float)C * 960.f;
        float mu = s / n;
        rstd[t] = rsqrtf(q / n - mu * mu + 1e-5f);
    }
}

// ---- softmax over last dim (960); IN mean cancels per row ----
__global__ __launch_bounds__(256)
void softmax_kernel(bf16* __restrict__ S, const float* __restrict__ rstd, int C) {
    __shared__ float x[960];
    __shared__ float red[4];
    long r = blockIdx.x;
    int t = threadIdx.x;
    float rs = rstd[r / C];
    bf16* row = S + r * 960;
    float mx = -3.4e38f;
    for (int i = t; i < 960; i += 256) {
        float v = ld1f(row + i) * rs; x[i] = v; mx = fmaxf(mx, v);
    }
    float M = blockMax256(mx, red);
    float s = 0.f;
    for (int i = t; i < 960; i += 256) { float e = __expf(x[i] - M); x[i] = e; s += e; }
    float Ssum = blockSum256(s, red);
    float inv = 1.f / Ssum;
    for (int i = t; i < 960; i += 256) st1(row + i, x[i] * inv);
}

extern "C" void kernel_launch(void* const* d_in, const int* in_sizes, int n_in,
                              void* d_out, int out_size, void* d_ws, size_t ws_size,
                              hipStream_t stream) {
    (void)in_sizes; (void)n_in; (void)out_size; (void)ws_size;
    const int Cs[4] = {64, 128, 256, 512};
    const float *emb[4], *ang[4], *anb[4], *Wq[4], *Wo[4], *fng[4], *fnb[4], *w1[4], *b1[4], *w2[4], *b2[4];
    for (int i = 0; i < 4; i++) {
        const int base = i * 11;
        emb[i] = (const float*)d_in[base + 0];
        ang[i] = (const float*)d_in[base + 1];
        anb[i] = (const float*)d_in[base + 2];
        Wq[i]  = (const float*)d_in[base + 3];
        Wo[i]  = (const float*)d_in[base + 4];
        fng[i] = (const float*)d_in[base + 5];
        fnb[i] = (const float*)d_in[base + 6];
        w1[i]  = (const float*)d_in[base + 7];
        b1[i]  = (const float*)d_in[base + 8];
        w2[i]  = (const float*)d_in[base + 9];
        b2[i]  = (const float*)d_in[base + 10];
    }
    const float* anAg = (const float*)d_in[44];
    const float* anAb = (const float*)d_in[45];
    const float* Wk   = (const float*)d_in[46];
    const float* Wv   = (const float*)d_in[47];

    const int NT = 3136;
    // ws layout (bytes), total 102,024,768 (<= 102.2 MB confirmed in R6)
    char* wsb = (char*)d_ws;
    bf16*   ea    = (bf16*)(wsb);                    // [3136,960]
    bf16*   KT    = (bf16*)(wsb + 6021120);          // [4][960][3136]
    bf16*   Vb    = (bf16*)(wsb + 30105600);         // [4][3136][960]
    bf16*   Qb    = (bf16*)(wsb + 54190080);         // QT / ctx tmp / hid
    bf16*   Sb    = (bf16*)(wsb + 67035136);         // [16][C][960]; wk/wv bf16 early
    bf16*   cxall = (bf16*)(wsb + 82763776);         // first-LN out, all branches
    bf16*   cxb   = (bf16*)(wsb + 88784896);         // ctx / post-res LN
    bf16*   xb    = (bf16*)(wsb + 91996160);         // residual
    bf16*   wtb   = (bf16*)(wsb + 95207424);         // per-branch weights, reused (6.82 MB)
    float2* part  = (float2*)(wsb + 102023168);      // [192]
    float*  rstdb = (float*)(wsb + 102024704);       // [16]

    bf16* wkb = Sb;                 // Sb region free until branch-0 scores
    bf16* wvb = Sb + 3686400;
    const long cxoff[4] = {0, 64L * NT, 192L * NT, 448L * NT};

    float* out = (float*)d_out;
    const long ooff[4] = {0, 200704, 602112, 1404928};
    const float scale = 0.03227486121f;  // 1/sqrt(960)

    // Wk/Wv -> bf16 (disjoint targets, grid-stride — no races)
    {
        Cvt4 a;
        a.s[0] = Wk; a.d[0] = (unsigned short*)wkb; a.n[0] = 3686400;
        a.s[1] = Wv; a.d[1] = (unsigned short*)wvb; a.n[1] = 3686400;
        a.s[2] = nullptr; a.s[3] = nullptr; a.d[2] = a.d[3] = nullptr; a.n[2] = a.n[3] = 0;
        cvt_kernel<<<512, 256, 0, stream>>>(a);
    }
    ln_concat_kernel<<<3136, 256, 0, stream>>>(emb[0], emb[1], emb[2], emb[3], anAg, anAb, ea);
    {
        LN4 a;
        for (int i = 0; i < 4; i++) {
            a.x[i] = emb[i]; a.g[i] = ang[i]; a.b[i] = anb[i];
            a.y[i] = cxall + cxoff[i]; a.C[i] = Cs[i];
        }
        ln4_kernel<<<dim3(3136, 4), 256, 0, stream>>>(a);
    }
    // KT[h] = (ea @ Wk[h]^T)^T ; V[h] = ea @ Wv[h]^T
    mfma2<128, 128, bf16, float, true><<<dim3(8, 25, 4), 256, 0, stream>>>(
        ea, 0, 0, 960, wkb, 921600, 0, 960, KT, 3010560, 0, NT,
        nullptr, (const float*)nullptr, NT, 960, 960, 1.f, 0);
    mfma2<128, 128, bf16, float, false><<<dim3(8, 25, 4), 256, 0, stream>>>(
        ea, 0, 0, 960, wvb, 921600, 0, 960, Vb, 3010560, 0, 960,
        nullptr, (const float*)nullptr, NT, 960, 960, 1.f, 0);

    for (int i = 0; i < 4; i++) {
        const int C = Cs[i];
        const long C2 = (long)C * C;
        // per-branch weight conversion into reused wtb: 13*C^2 elems, correct offsets
        bf16* wqb = wtb;
        bf16* wob = wtb + 4 * C2;
        bf16* w1b = wtb + 5 * C2;
        bf16* w2b = wtb + 9 * C2;
        {
            Cvt4 a;
            a.s[0] = Wq[i]; a.d[0] = (unsigned short*)wqb; a.n[0] = 4 * C2;
            a.s[1] = Wo[i]; a.d[1] = (unsigned short*)wob; a.n[1] = C2;
            a.s[2] = w1[i]; a.d[2] = (unsigned short*)w1b; a.n[2] = 4 * C2;
            a.s[3] = w2[i]; a.d[3] = (unsigned short*)w2b; a.n[3] = 4 * C2;
            cvt_kernel<<<512, 256, 0, stream>>>(a);
        }
        // QT[h] = (cx @ Wq[h]^T)^T
        mfma2<64, 64, bf16, float, true><<<dim3(C / 64, 49, 4), 256, 0, stream>>>(
            cxall + cxoff[i], 0, 0, C, wqb, C2, 0, C, Qb, (long)C * NT, 0, NT,
            nullptr, (const float*)nullptr, NT, C, C, 1.f, 0);
        // S[z] = scale * QT-slab @ KT-slab^T  (M=C, N=960, K=784)
        if (C >= 256)
            mfma2<128, 128, bf16, float, false><<<dim3(8, C / 128, 16), 256, 0, stream>>>(
                Qb, (long)C * NT, 784, NT, KT, 3010560, 784, NT,
                Sb, (long)C * 960, (long)4 * C * 960, 960,
                nullptr, (const float*)nullptr, C, 960, 784, scale, 0);
        else
            mfma2<64, 64, bf16, float, false><<<dim3(15, C / 64, 16), 256, 0, stream>>>(
                Qb, (long)C * NT, 784, NT, KT, 3010560, 784, NT,
                Sb, (long)C * 960, (long)4 * C * 960, 960,
                nullptr, (const float*)nullptr, C, 960, 784, scale, 0);
        // instance-norm rstd + softmax
        inorm_part_kernel<<<192, 256, 0, stream>>>(Sb, part, C);
        inorm_fin_kernel<<<1, 64, 0, stream>>>(part, rstdb, C, 16);
        softmax_kernel<<<16 * C, 256, 0, stream>>>(Sb, rstdb, C);
        // tmp[h] = V-slab @ S[z]^T  (M=784, N=C, K=960)
        if (C == 512)
            mfma2<128, 128, bf16, float, false><<<dim3(C / 128, 7, 16), 256, 0, stream>>>(
                Vb, 3010560, 784L * 960, 960, Sb, (long)C * 960, (long)4 * C * 960, 960,
                Qb, (long)NT * C, 784L * C, C,
                nullptr, (const float*)nullptr, 784, C, 960, 1.f, 0);
        else
            mfma2<64, 64, bf16, float, false><<<dim3(C / 64, 13, 16), 256, 0, stream>>>(
                Vb, 3010560, 784L * 960, 960, Sb, (long)C * 960, (long)4 * C * 960, 960,
                Qb, (long)NT * C, 784L * C, C,
                nullptr, (const float*)nullptr, 784, C, 960, 1.f, 0);
        ctx_sum_kernel<<<(int)(((long)NT * C) / 1024), 256, 0, stream>>>(
            Qb, cxb, (long)NT * C);
        // x = emb + ctx @ Wo^T  -> bf16
        mfma2<64, 64, bf16, float, false><<<dim3(C / 64, 49, 1), 256, 0, stream>>>(
            cxb, 0, 0, C, wob, 0, 0, C, xb, 0, 0, C,
            nullptr, emb[i], NT, C, C, 1.f, 0);
        // lnx = LN(x) -> bf16
        ln_rows_kernel<<<NT, 256, 0, stream>>>(xb, fng[i], fnb[i], cxb, C);
        // hid = gelu(lnx @ w1^T + b1) -> bf16
        if (C >= 256)
            mfma2<128, 128, bf16, float, false><<<dim3(4 * C / 128, 25, 1), 256, 0, stream>>>(
                cxb, 0, 0, C, w1b, 0, 0, C, Qb, 0, 0, 4 * C,
                b1[i], (const float*)nullptr, NT, 4 * C, C, 1.f, 1);
        else
            mfma2<64, 64, bf16, float, false><<<dim3(4 * C / 64, 49, 1), 256, 0, stream>>>(
                cxb, 0, 0, C, w1b, 0, 0, C, Qb, 0, 0, 4 * C,
                b1[i], (const float*)nullptr, NT, 4 * C, C, 1.f, 1);
        // out = x + hid @ w2^T + b2  (fp32 store to d_out)
        mfma2<64, 64, float, bf16, false><<<dim3(C / 64, 49, 1), 256, 0, stream>>>(
            Qb, 0, 0, 4 * C, w2b, 0, 0, 4 * C, out + ooff[i], 0, 0, C,
            b2[i], xb, NT, C, 4 * C, 1.f, 0);
    }
}